// Round 1
// baseline (1494.887 us; speedup 1.0000x reference)
//
#include <hip/hip_runtime.h>

// GCN 2-layer: dims fixed per reference
#define DIN  512
#define DHID 256
#define DOF  128

// ---------------- degree + norm ----------------
__global__ void count_deg(const int* __restrict__ src, const int* __restrict__ dst,
                          float* __restrict__ deg_out, float* __restrict__ deg_in, int e) {
    int i = blockIdx.x * blockDim.x + threadIdx.x;
    if (i < e) {
        atomicAdd(&deg_out[src[i]], 1.0f);
        atomicAdd(&deg_in[dst[i]], 1.0f);
    }
}

__global__ void make_norm(float* __restrict__ a, float* __restrict__ b, int n) {
    int i = blockIdx.x * blockDim.x + threadIdx.x;
    if (i < n) {
        a[i] = rsqrtf(fmaxf(a[i], 1.0f));
        b[i] = rsqrtf(fmaxf(b[i], 1.0f));
    }
}

// ---------------- H = (X * norm_src[:,None]) @ W ----------------
// block = N threads; each block computes ROWS rows of H.
// LDS holds ROWS x K pre-scaled X rows. Thread j owns output column j.
template<int K, int N, int ROWS>
__global__ __launch_bounds__(N) void gemm_norm(const float* __restrict__ X,
                                               const float* __restrict__ norm,
                                               const float* __restrict__ W,
                                               float* __restrict__ H, int n) {
    __shared__ float xs[ROWS * K];
    const int r0 = blockIdx.x * ROWS;
    const int tid = threadIdx.x;

    for (int i = tid; i < ROWS * K; i += N) {
        int r = i >> 9;              // i / K only valid if K==512; compute generically:
        r = i / K;
        int k = i - r * K;
        int row = r0 + r;
        xs[i] = (row < n) ? X[(long)row * K + k] * norm[row] : 0.0f;
    }
    __syncthreads();

    float acc[ROWS];
#pragma unroll
    for (int r = 0; r < ROWS; ++r) acc[r] = 0.0f;

    for (int k = 0; k < K; ++k) {
        float w = W[k * N + tid];          // coalesced across threads
#pragma unroll
        for (int r = 0; r < ROWS; ++r)
            acc[r] += xs[r * K + k] * w;   // LDS broadcast (same addr per wave)
    }

#pragma unroll
    for (int r = 0; r < ROWS; ++r) {
        int row = r0 + r;
        if (row < n) H[(long)row * N + tid] = acc[r];
    }
}

// ---------------- AGG[dst] += H[src]  (segment_sum over edges) ----------------
template<int F>
__global__ void scatter_add(const float* __restrict__ H, const int* __restrict__ src,
                            const int* __restrict__ dst, float* __restrict__ AGG, int e) {
    long idx = (long)blockIdx.x * blockDim.x + threadIdx.x;
    long tot = (long)e * F;
    if (idx >= tot) return;
    int edge = (int)(idx / F);     // F is power of 2 -> shift
    int j = (int)(idx & (F - 1));
    int s = src[edge];
    int d = dst[edge];
    atomicAdd(&AGG[(long)d * F + j], H[(long)s * F + j]);
}

// ---------------- A = maybe_relu(A * norm_dst[:,None] + bias) ----------------
template<int F, bool RELU>
__global__ void finalize(float* __restrict__ A, const float* __restrict__ norm,
                         const float* __restrict__ bias, int n) {
    long idx = (long)blockIdx.x * blockDim.x + threadIdx.x;
    long tot = (long)n * F;
    if (idx >= tot) return;
    int row = (int)(idx / F);
    int j = (int)(idx & (F - 1));
    float v = A[idx] * norm[row] + bias[j];
    if (RELU) v = fmaxf(v, 0.0f);
    A[idx] = v;
}

extern "C" void kernel_launch(void* const* d_in, const int* in_sizes, int n_in,
                              void* d_out, int out_size, void* d_ws, size_t ws_size,
                              hipStream_t stream) {
    const float* features = (const float*)d_in[0];
    const int*   src      = (const int*)d_in[1];
    const int*   dst      = (const int*)d_in[2];
    const float* W1       = (const float*)d_in[3];
    const float* b1       = (const float*)d_in[4];
    const float* W2       = (const float*)d_in[5];
    const float* b2       = (const float*)d_in[6];
    float* out = (float*)d_out;

    const int n = in_sizes[0] / DIN;   // 50000
    const int e = in_sizes[1];         // 800000

    // ---- workspace layout (bytes) ----
    char* ws = (char*)d_ws;
    size_t off = 0;
    auto alloc = [&](size_t bytes) { size_t o = off; off += (bytes + 255) & ~(size_t)255; return o; };
    size_t o_degout = alloc((size_t)n * 4);          // deg_out -> norm_src (in place)
    size_t o_degin  = alloc((size_t)n * 4);          // deg_in  -> norm_dst
    size_t o_h1     = alloc((size_t)n * DHID * 4);   // h1 ; later reused as h2
    size_t o_x1     = alloc((size_t)n * DHID * 4);   // agg1 -> x1 (in place)
    (void)ws_size;

    float* deg_out = (float*)(ws + o_degout);
    float* deg_in  = (float*)(ws + o_degin);
    float* h1      = (float*)(ws + o_h1);
    float* x1      = (float*)(ws + o_x1);
    float* h2      = (float*)(ws + o_h1);            // alias: h1 dead after scatter1

    // ---- zero accumulators (graph-capture-safe async memsets) ----
    hipMemsetAsync(ws, 0, o_h1, stream);                              // both deg arrays
    hipMemsetAsync(x1, 0, (size_t)n * DHID * 4, stream);              // agg1
    hipMemsetAsync(out, 0, (size_t)out_size * 4, stream);             // agg2

    // ---- degrees + norms ----
    count_deg<<<(e + 255) / 256, 256, 0, stream>>>(src, dst, deg_out, deg_in, e);
    make_norm<<<(n + 255) / 256, 256, 0, stream>>>(deg_out, deg_in, n);

    // ---- layer 1 ----
    constexpr int ROWS = 16;
    gemm_norm<DIN, DHID, ROWS><<<(n + ROWS - 1) / ROWS, DHID, 0, stream>>>(
        features, deg_out, W1, h1, n);
    {
        long tot = (long)e * DHID;
        scatter_add<DHID><<<(unsigned)((tot + 255) / 256), 256, 0, stream>>>(h1, src, dst, x1, e);
    }
    {
        long tot = (long)n * DHID;
        finalize<DHID, true><<<(unsigned)((tot + 255) / 256), 256, 0, stream>>>(x1, deg_in, b1, n);
    }

    // ---- layer 2 ----
    gemm_norm<DHID, DOF, ROWS><<<(n + ROWS - 1) / ROWS, DOF, 0, stream>>>(
        x1, deg_out, W2, h2, n);
    {
        long tot = (long)e * DOF;
        scatter_add<DOF><<<(unsigned)((tot + 255) / 256), 256, 0, stream>>>(h2, src, dst, out, e);
    }
    {
        long tot = (long)n * DOF;
        finalize<DOF, false><<<(unsigned)((tot + 255) / 256), 256, 0, stream>>>(out, deg_in, b2, n);
    }
}

// Round 5
// 721.837 us; speedup vs baseline: 2.0709x; 2.0709x over previous
//
#include <hip/hip_runtime.h>

#define DIN  512
#define DHID 256
#define DOF  128

// ---------------- degree counting (int) ----------------
__global__ void count_deg(const int* __restrict__ src, const int* __restrict__ dst,
                          int* __restrict__ deg_out, int* __restrict__ deg_in, int e) {
    int i = blockIdx.x * blockDim.x + threadIdx.x;
    if (i < e) {
        atomicAdd(&deg_out[src[i]], 1);
        atomicAdd(&deg_in[dst[i]], 1);
    }
}

// norms: rsqrt(max(deg,1))
__global__ void make_norm(const int* __restrict__ deg_out, const int* __restrict__ deg_in,
                          float* __restrict__ norm_src, float* __restrict__ norm_dst, int n) {
    int i = blockIdx.x * blockDim.x + threadIdx.x;
    if (i < n) {
        norm_src[i] = rsqrtf(fmaxf((float)deg_out[i], 1.0f));
        norm_dst[i] = rsqrtf(fmaxf((float)deg_in[i], 1.0f));
    }
}

// ---------------- exclusive scan over deg_in -> rowptr[n+1] ----------------
// single block, 1024 threads, n = 50000 (49 elems/thread)
__global__ __launch_bounds__(1024) void scan_rowptr(const int* __restrict__ deg,
                                                    int* __restrict__ rowptr, int n) {
    __shared__ int part[1024];
    const int tid = threadIdx.x;
    const int per = (n + 1023) / 1024;
    const int s = tid * per;
    const int e0 = min(s + per, n);
    int sum = 0;
    for (int i = s; i < e0; ++i) sum += deg[i];
    part[tid] = sum;
    __syncthreads();
    // Hillis-Steele inclusive scan in LDS
    for (int off = 1; off < 1024; off <<= 1) {
        int v = (tid >= off) ? part[tid - off] : 0;
        __syncthreads();
        part[tid] += v;
        __syncthreads();
    }
    int excl = (tid == 0) ? 0 : part[tid - 1];
    for (int i = s; i < e0; ++i) { rowptr[i] = excl; excl += deg[i]; }
    if (tid == 1023) rowptr[n] = part[1023];
}

// ---------------- bucket fill: csr_src sorted by dst ----------------
__global__ void fill_csr(const int* __restrict__ src, const int* __restrict__ dst,
                         const int* __restrict__ rowptr, int* __restrict__ cursor,
                         int* __restrict__ csr_src, int e) {
    int i = blockIdx.x * blockDim.x + threadIdx.x;
    if (i < e) {
        int d = dst[i];
        int p = atomicAdd(&cursor[d], 1);
        csr_src[rowptr[d] + p] = src[i];
    }
}

// ---------------- H = (X * norm_src[:,None]) @ W  (fp32, LDS-broadcast) ----------------
template<int K, int N, int ROWS>
__global__ __launch_bounds__(N) void gemm_norm(const float* __restrict__ X,
                                               const float* __restrict__ norm,
                                               const float* __restrict__ W,
                                               float* __restrict__ H, int n) {
    __shared__ float xs[ROWS * K];
    const int r0 = blockIdx.x * ROWS;
    const int tid = threadIdx.x;

    for (int i = tid; i < ROWS * K; i += N) {
        int r = i / K;
        int k = i - r * K;
        int row = r0 + r;
        xs[i] = (row < n) ? X[(long)row * K + k] * norm[row] : 0.0f;
    }
    __syncthreads();

    float acc[ROWS];
#pragma unroll
    for (int r = 0; r < ROWS; ++r) acc[r] = 0.0f;

    for (int k = 0; k < K; ++k) {
        float w = W[k * N + tid];
#pragma unroll
        for (int r = 0; r < ROWS; ++r)
            acc[r] += xs[r * K + k] * w;
    }

#pragma unroll
    for (int r = 0; r < ROWS; ++r) {
        int row = r0 + r;
        if (row < n) H[(long)row * N + tid] = acc[r];
    }
}

// ---------------- out[d] = relu?(norm_dst[d] * sum_{s in N(d)} H[s] + bias) ----------------
// one block of F threads per destination node; row accumulated in registers, written once
template<int F, bool RELU>
__global__ __launch_bounds__(F) void aggregate(const float* __restrict__ H,
                                               const int* __restrict__ rowptr,
                                               const int* __restrict__ csr_src,
                                               const float* __restrict__ norm_dst,
                                               const float* __restrict__ bias,
                                               float* __restrict__ out, int n) {
    const int d = blockIdx.x;
    if (d >= n) return;
    const int tid = threadIdx.x;
    int k = rowptr[d];
    const int end = rowptr[d + 1];

    float acc = 0.0f;
    for (; k + 1 < end; k += 2) {                 // 2-way ILP on the gather
        int s0 = csr_src[k];
        int s1 = csr_src[k + 1];
        float a0 = H[(long)s0 * F + tid];
        float a1 = H[(long)s1 * F + tid];
        acc += a0;
        acc += a1;
    }
    if (k < end) acc += H[(long)csr_src[k] * F + tid];

    float v = acc * norm_dst[d] + bias[tid];
    if (RELU) v = fmaxf(v, 0.0f);
    out[(long)d * F + tid] = v;
}

extern "C" void kernel_launch(void* const* d_in, const int* in_sizes, int n_in,
                              void* d_out, int out_size, void* d_ws, size_t ws_size,
                              hipStream_t stream) {
    const float* features = (const float*)d_in[0];
    const int*   src      = (const int*)d_in[1];
    const int*   dst      = (const int*)d_in[2];
    const float* W1       = (const float*)d_in[3];
    const float* b1       = (const float*)d_in[4];
    const float* W2       = (const float*)d_in[5];
    const float* b2       = (const float*)d_in[6];
    float* out = (float*)d_out;

    const int n = in_sizes[0] / DIN;   // 50000
    const int e = in_sizes[1];         // 800000

    // ---- workspace layout ----
    char* ws = (char*)d_ws;
    size_t off = 0;
    auto alloc = [&](size_t bytes) { size_t o = off; off += (bytes + 255) & ~(size_t)255; return o; };
    size_t o_degi   = alloc((size_t)n * 4);            // deg_in (int)  [memset 0]
    size_t o_dego   = alloc((size_t)n * 4);            // deg_out (int) [memset 0]
    size_t o_cursor = alloc((size_t)n * 4);            // bucket cursors [memset 0]
    size_t o_nsrc   = alloc((size_t)n * 4);            // norm_src (f32)
    size_t o_ndst   = alloc((size_t)n * 4);            // norm_dst (f32)
    size_t o_rowptr = alloc((size_t)(n + 1) * 4);      // rowptr (int)
    size_t o_csr    = alloc((size_t)e * 4);            // csr_src (int)
    size_t o_h1     = alloc((size_t)n * DHID * 4);     // h1 ; reused as h2
    size_t o_x1     = alloc((size_t)n * DHID * 4);     // x1 (layer-1 output)
    (void)ws_size;

    int*   deg_in   = (int*)(ws + o_degi);
    int*   deg_out  = (int*)(ws + o_dego);
    int*   cursor   = (int*)(ws + o_cursor);
    float* norm_src = (float*)(ws + o_nsrc);
    float* norm_dst = (float*)(ws + o_ndst);
    int*   rowptr   = (int*)(ws + o_rowptr);
    int*   csr_src  = (int*)(ws + o_csr);
    float* h1       = (float*)(ws + o_h1);
    float* x1       = (float*)(ws + o_x1);
    float* h2       = (float*)(ws + o_h1);             // alias: h1 dead after aggregate1

    // zero the three int accumulator arrays (contiguous at front of ws)
    hipMemsetAsync(ws, 0, o_nsrc, stream);

    // ---- graph preprocessing ----
    count_deg<<<(e + 255) / 256, 256, 0, stream>>>(src, dst, deg_out, deg_in, e);
    make_norm<<<(n + 255) / 256, 256, 0, stream>>>(deg_out, deg_in, norm_src, norm_dst, n);
    scan_rowptr<<<1, 1024, 0, stream>>>(deg_in, rowptr, n);
    fill_csr<<<(e + 255) / 256, 256, 0, stream>>>(src, dst, rowptr, cursor, csr_src, e);

    // ---- layer 1: h1 = (X*norm_src)@W1 ; x1 = relu(norm_dst * agg(h1) + b1) ----
    constexpr int ROWS = 16;
    gemm_norm<DIN, DHID, ROWS><<<(n + ROWS - 1) / ROWS, DHID, 0, stream>>>(
        features, norm_src, W1, h1, n);
    aggregate<DHID, true><<<n, DHID, 0, stream>>>(h1, rowptr, csr_src, norm_dst, b1, x1, n);

    // ---- layer 2: h2 = (x1*norm_src)@W2 ; out = norm_dst * agg(h2) + b2 ----
    gemm_norm<DHID, DOF, ROWS><<<(n + ROWS - 1) / ROWS, DOF, 0, stream>>>(
        x1, norm_src, W2, h2, n);
    aggregate<DOF, false><<<n, DOF, 0, stream>>>(h2, rowptr, csr_src, norm_dst, b2, out, n);
}

// Round 7
// 436.441 us; speedup vs baseline: 3.4252x; 1.6539x over previous
//
#include <hip/hip_runtime.h>

#define DIN  512
#define DHID 256
#define DOF  128

typedef _Float16 f16;
typedef _Float16 f16x8 __attribute__((ext_vector_type(8)));
typedef float f32x4 __attribute__((ext_vector_type(4)));

// ---------------- degree counting (int) ----------------
__global__ void count_deg(const int* __restrict__ src, const int* __restrict__ dst,
                          int* __restrict__ deg_out, int* __restrict__ deg_in, int e) {
    int i = blockIdx.x * blockDim.x + threadIdx.x;
    if (i < e) {
        atomicAdd(&deg_out[src[i]], 1);
        atomicAdd(&deg_in[dst[i]], 1);
    }
}

__global__ void make_norm(const int* __restrict__ deg_out, const int* __restrict__ deg_in,
                          float* __restrict__ norm_src, float* __restrict__ norm_dst, int n) {
    int i = blockIdx.x * blockDim.x + threadIdx.x;
    if (i < n) {
        norm_src[i] = rsqrtf(fmaxf((float)deg_out[i], 1.0f));
        norm_dst[i] = rsqrtf(fmaxf((float)deg_in[i], 1.0f));
    }
}

// ---------------- exclusive scan over deg_in -> rowptr[n+1] ----------------
__global__ __launch_bounds__(1024) void scan_rowptr(const int* __restrict__ deg,
                                                    int* __restrict__ rowptr, int n) {
    __shared__ int part[1024];
    const int tid = threadIdx.x;
    const int per = (n + 1023) / 1024;
    const int s = tid * per;
    const int e0 = min(s + per, n);
    int sum = 0;
    for (int i = s; i < e0; ++i) sum += deg[i];
    part[tid] = sum;
    __syncthreads();
    for (int off = 1; off < 1024; off <<= 1) {
        int v = (tid >= off) ? part[tid - off] : 0;
        __syncthreads();
        part[tid] += v;
        __syncthreads();
    }
    int excl = (tid == 0) ? 0 : part[tid - 1];
    for (int i = s; i < e0; ++i) { rowptr[i] = excl; excl += deg[i]; }
    if (tid == 1023) rowptr[n] = part[1023];
}

// ---------------- bucket fill: csr_src sorted by dst ----------------
__global__ void fill_csr(const int* __restrict__ src, const int* __restrict__ dst,
                         const int* __restrict__ rowptr, int* __restrict__ cursor,
                         int* __restrict__ csr_src, int e) {
    int i = blockIdx.x * blockDim.x + threadIdx.x;
    if (i < e) {
        int d = dst[i];
        int p = atomicAdd(&cursor[d], 1);
        csr_src[rowptr[d] + p] = src[i];
    }
}

// ---------------- W -> f16 transposed: wt[c][k] = (f16)W[k][c] ----------------
__global__ void transpose_w(const float* __restrict__ W1, const float* __restrict__ W2,
                            f16* __restrict__ w1t, f16* __restrict__ w2t) {
    int t = blockIdx.x * blockDim.x + threadIdx.x;
    if (t < DIN * DHID) {
        int k = t / DHID, c = t % DHID;
        w1t[c * DIN + k] = (f16)W1[t];
    } else {
        int u = t - DIN * DHID;
        if (u < DHID * DOF) {
            int k = u / DOF, c = u % DOF;
            w2t[c * DHID + k] = (f16)W2[u];
        }
    }
}

// ---------------- MFMA GEMM: H[M][N](f16) = (A * norm[:,None]) @ Bt^T ----------------
// A: f32 [M][K] (A_F32, scaled by norm) or f16 [M][K] (pre-scaled). Bt: f16 [N][K].
// Block 256 thr = 4 waves; tile BM=128, BN=128, BK=32; wave -> 64x64 (4x4 frags of 16x16x32).
template<int K, int N, bool A_F32>
__global__ __launch_bounds__(256) void mfma_gemm(const void* __restrict__ Aptr,
                                                 const float* __restrict__ norm,
                                                 const f16* __restrict__ Bt,
                                                 f16* __restrict__ H, int M) {
    constexpr int BM = 128, BN = 128, BK = 32;
    __shared__ __align__(16) f16 smem[BM * BN];     // 32KB; k-loop uses first 16KB
    f16* As = smem;                                  // [128][32] row-major
    f16* Bs = smem + BM * BK;                        // [128 cols][32], 16B-XOR-swizzled

    const int rbase = blockIdx.x * BM;
    const int nb = blockIdx.y * BN;
    const int tid = threadIdx.x;
    const int l = tid & 63, wid = tid >> 6;
    const int wr = wid >> 1, wc = wid & 1;
    const int fr = l & 15, kg = l >> 4;

    f32x4 acc[4][4] = {};

    for (int kt = 0; kt < K / BK; ++kt) {
        const int k0 = kt * BK;
        __syncthreads();
#pragma unroll
        for (int j = 0; j < 2; ++j) {
            int u = tid + j * 256;
            {   // A unit: 16B of one row
                int row = u >> 2, un = u & 3;
                int grow = rbase + row;
                f16x8 v = {};
                if (grow < M) {
                    if (A_F32) {
                        const float* A = (const float*)Aptr + (long)grow * K + k0 + un * 8;
                        float s = norm[grow];
                        float4 a0 = *(const float4*)A;
                        float4 a1 = *(const float4*)(A + 4);
                        v[0] = (f16)(a0.x * s); v[1] = (f16)(a0.y * s);
                        v[2] = (f16)(a0.z * s); v[3] = (f16)(a0.w * s);
                        v[4] = (f16)(a1.x * s); v[5] = (f16)(a1.y * s);
                        v[6] = (f16)(a1.z * s); v[7] = (f16)(a1.w * s);
                    } else {
                        v = *(const f16x8*)((const f16*)Aptr + (long)grow * K + k0 + un * 8);
                    }
                }
                *(f16x8*)&As[row * BK + un * 8] = v;
            }
            {   // B unit
                int c = u >> 2, un = u & 3;
                f16x8 v = *(const f16x8*)(Bt + (long)(nb + c) * K + k0 + un * 8);
                int idx = (c * BK + un * 8) ^ ((c & 7) << 3);
                *(f16x8*)&Bs[idx] = v;
            }
        }
        __syncthreads();

        f16x8 af[4], bf[4];
#pragma unroll
        for (int m = 0; m < 4; ++m)
            af[m] = *(const f16x8*)&As[(wr * 64 + m * 16 + fr) * BK + kg * 8];
#pragma unroll
        for (int nf = 0; nf < 4; ++nf) {
            int c = wc * 64 + nf * 16 + fr;
            int idx = (c * BK + kg * 8) ^ ((c & 7) << 3);
            bf[nf] = *(const f16x8*)&Bs[idx];
        }
#pragma unroll
        for (int m = 0; m < 4; ++m)
#pragma unroll
            for (int nf = 0; nf < 4; ++nf)
                acc[m][nf] = __builtin_amdgcn_mfma_f32_16x16x32_f16(af[m], bf[nf], acc[m][nf], 0, 0, 0);
    }

    __syncthreads();
    // restage C tile in LDS (f16) for coalesced stores
#pragma unroll
    for (int m = 0; m < 4; ++m)
#pragma unroll
        for (int nf = 0; nf < 4; ++nf)
#pragma unroll
            for (int i = 0; i < 4; ++i) {
                int row = wr * 64 + m * 16 + (l >> 4) * 4 + i;
                int col = wc * 64 + nf * 16 + (l & 15);
                smem[row * BN + col] = (f16)acc[m][nf][i];
            }
    __syncthreads();
#pragma unroll
    for (int j = 0; j < 8; ++j) {
        int u = tid + j * 256;
        int row = u >> 4, cu = u & 15;
        int grow = rbase + row;
        if (grow < M)
            *(f16x8*)(H + (long)grow * N + nb + cu * 8) =
                *(const f16x8*)&smem[row * BN + cu * 8];
    }
}

// ---------------- gather-aggregate over CSR, fused epilogue ----------------
// out[d] = (relu?)(norm_dst[d] * sum H[s] + bias) (* norm_src[d] if FOLD), f16 or f32 out
template<int F, bool RELU, bool FOLD, bool OUT_F16>
__global__ __launch_bounds__(F) void aggregate_f16(const f16* __restrict__ H,
                                                   const int* __restrict__ rowptr,
                                                   const int* __restrict__ csr_src,
                                                   const float* __restrict__ norm_dst,
                                                   const float* __restrict__ norm_src,
                                                   const float* __restrict__ bias,
                                                   void* __restrict__ outp, int n) {
    const int d = blockIdx.x;
    if (d >= n) return;
    const int tid = threadIdx.x;
    int k = rowptr[d];
    const int end = rowptr[d + 1];
    float acc = 0.f;
    for (; k + 1 < end; k += 2) {
        int s0 = csr_src[k], s1 = csr_src[k + 1];
        float a0 = (float)H[(long)s0 * F + tid];
        float a1 = (float)H[(long)s1 * F + tid];
        acc += a0; acc += a1;
    }
    if (k < end) acc += (float)H[(long)csr_src[k] * F + tid];
    float v = acc * norm_dst[d] + bias[tid];
    if (RELU) v = fmaxf(v, 0.f);
    if (FOLD) v *= norm_src[d];
    if (OUT_F16) ((f16*)outp)[(long)d * F + tid] = (f16)v;
    else        ((float*)outp)[(long)d * F + tid] = v;
}

extern "C" void kernel_launch(void* const* d_in, const int* in_sizes, int n_in,
                              void* d_out, int out_size, void* d_ws, size_t ws_size,
                              hipStream_t stream) {
    const float* features = (const float*)d_in[0];
    const int*   src      = (const int*)d_in[1];
    const int*   dst      = (const int*)d_in[2];
    const float* W1       = (const float*)d_in[3];
    const float* b1       = (const float*)d_in[4];
    const float* W2       = (const float*)d_in[5];
    const float* b2       = (const float*)d_in[6];
    float* out = (float*)d_out;

    const int n = in_sizes[0] / DIN;   // 50000
    const int e = in_sizes[1];         // 800000

    // ---- workspace layout ----
    char* ws = (char*)d_ws;
    size_t off = 0;
    auto alloc = [&](size_t bytes) { size_t o = off; off += (bytes + 255) & ~(size_t)255; return o; };
    size_t o_degi   = alloc((size_t)n * 4);            // deg_in  [memset 0]
    size_t o_dego   = alloc((size_t)n * 4);            // deg_out [memset 0]
    size_t o_cursor = alloc((size_t)n * 4);            // cursors [memset 0]
    size_t o_nsrc   = alloc((size_t)n * 4);            // norm_src
    size_t o_ndst   = alloc((size_t)n * 4);            // norm_dst
    size_t o_rowptr = alloc((size_t)(n + 1) * 4);      // rowptr
    size_t o_csr    = alloc((size_t)e * 4);            // csr_src
    size_t o_w1t    = alloc((size_t)DIN * DHID * 2);   // W1^T f16
    size_t o_w2t    = alloc((size_t)DHID * DOF * 2);   // W2^T f16
    size_t o_h1     = alloc((size_t)n * DHID * 2);     // h1 f16
    size_t o_x1     = alloc((size_t)n * DHID * 2);     // x1 f16 (pre-scaled by norm_src)
    size_t o_h2     = alloc((size_t)n * DOF * 2);      // h2 f16
    (void)ws_size;

    int*   deg_in   = (int*)(ws + o_degi);
    int*   deg_out  = (int*)(ws + o_dego);
    int*   cursor   = (int*)(ws + o_cursor);
    float* norm_src = (float*)(ws + o_nsrc);
    float* norm_dst = (float*)(ws + o_ndst);
    int*   rowptr   = (int*)(ws + o_rowptr);
    int*   csr_src  = (int*)(ws + o_csr);
    f16*   w1t      = (f16*)(ws + o_w1t);
    f16*   w2t      = (f16*)(ws + o_w2t);
    f16*   h1       = (f16*)(ws + o_h1);
    f16*   x1       = (f16*)(ws + o_x1);
    f16*   h2       = (f16*)(ws + o_h2);

    hipMemsetAsync(ws, 0, o_nsrc, stream);   // deg_in, deg_out, cursor

    // ---- graph preprocessing ----
    count_deg<<<(e + 255) / 256, 256, 0, stream>>>(src, dst, deg_out, deg_in, e);
    make_norm<<<(n + 255) / 256, 256, 0, stream>>>(deg_out, deg_in, norm_src, norm_dst, n);
    scan_rowptr<<<1, 1024, 0, stream>>>(deg_in, rowptr, n);
    fill_csr<<<(e + 255) / 256, 256, 0, stream>>>(src, dst, rowptr, cursor, csr_src, e);
    transpose_w<<<(DIN * DHID + DHID * DOF + 255) / 256, 256, 0, stream>>>(W1, W2, w1t, w2t);

    const int mtiles = (n + 127) / 128;      // 391

    // ---- layer 1 ----
    mfma_gemm<DIN, DHID, true><<<dim3(mtiles, DHID / 128), 256, 0, stream>>>(
        features, norm_src, w1t, h1, n);
    aggregate_f16<DHID, true, true, true><<<n, DHID, 0, stream>>>(
        h1, rowptr, csr_src, norm_dst, norm_src, b1, x1, n);

    // ---- layer 2 ----
    mfma_gemm<DHID, DOF, false><<<dim3(mtiles, DOF / 128), 256, 0, stream>>>(
        x1, nullptr, w2t, h2, n);
    aggregate_f16<DOF, false, false, false><<<n, DOF, 0, stream>>>(
        h2, rowptr, csr_src, norm_dst, norm_src, b2, out, n);
}

// Round 8
// 362.900 us; speedup vs baseline: 4.1193x; 1.2026x over previous
//
#include <hip/hip_runtime.h>
#include <type_traits>

#define DIN  512
#define DHID 256
#define DOF  128

typedef _Float16 f16;
typedef _Float16 f16x8 __attribute__((ext_vector_type(8)));
typedef _Float16 f16v4 __attribute__((ext_vector_type(4)));
typedef _Float16 f16v2 __attribute__((ext_vector_type(2)));
typedef float f32x4 __attribute__((ext_vector_type(4)));

// ---------------- degree counting (int) ----------------
__global__ void count_deg(const int* __restrict__ src, const int* __restrict__ dst,
                          int* __restrict__ deg_out, int* __restrict__ deg_in, int e) {
    int i = blockIdx.x * blockDim.x + threadIdx.x;
    if (i < e) {
        atomicAdd(&deg_out[src[i]], 1);
        atomicAdd(&deg_in[dst[i]], 1);
    }
}

__global__ void make_norm(const int* __restrict__ deg_out, const int* __restrict__ deg_in,
                          float* __restrict__ norm_src, float* __restrict__ norm_dst, int n) {
    int i = blockIdx.x * blockDim.x + threadIdx.x;
    if (i < n) {
        norm_src[i] = rsqrtf(fmaxf((float)deg_out[i], 1.0f));
        norm_dst[i] = rsqrtf(fmaxf((float)deg_in[i], 1.0f));
    }
}

// ---------------- exclusive scan over deg_in -> rowptr[n+1] ----------------
__global__ __launch_bounds__(1024) void scan_rowptr(const int* __restrict__ deg,
                                                    int* __restrict__ rowptr, int n) {
    __shared__ int part[1024];
    const int tid = threadIdx.x;
    const int per = (n + 1023) / 1024;
    const int s = tid * per;
    const int e0 = min(s + per, n);
    int sum = 0;
    for (int i = s; i < e0; ++i) sum += deg[i];
    part[tid] = sum;
    __syncthreads();
    for (int off = 1; off < 1024; off <<= 1) {
        int v = (tid >= off) ? part[tid - off] : 0;
        __syncthreads();
        part[tid] += v;
        __syncthreads();
    }
    int excl = (tid == 0) ? 0 : part[tid - 1];
    for (int i = s; i < e0; ++i) { rowptr[i] = excl; excl += deg[i]; }
    if (tid == 1023) rowptr[n] = part[1023];
}

// ---------------- bucket fill: csr_src sorted by dst ----------------
__global__ void fill_csr(const int* __restrict__ src, const int* __restrict__ dst,
                         const int* __restrict__ rowptr, int* __restrict__ cursor,
                         int* __restrict__ csr_src, int e) {
    int i = blockIdx.x * blockDim.x + threadIdx.x;
    if (i < e) {
        int d = dst[i];
        int p = atomicAdd(&cursor[d], 1);
        csr_src[rowptr[d] + p] = src[i];
    }
}

// ---------------- W -> f16 transposed: wt[c][k] = (f16)W[k][c] ----------------
__global__ void transpose_w(const float* __restrict__ W1, const float* __restrict__ W2,
                            f16* __restrict__ w1t, f16* __restrict__ w2t) {
    int t = blockIdx.x * blockDim.x + threadIdx.x;
    if (t < DIN * DHID) {
        int k = t / DHID, c = t % DHID;
        w1t[c * DIN + k] = (f16)W1[t];
    } else {
        int u = t - DIN * DHID;
        if (u < DHID * DOF) {
            int k = u / DOF, c = u % DOF;
            w2t[c * DHID + k] = (f16)W2[u];
        }
    }
}

// ---------------- MFMA GEMM: H[M][N](f16) = (A * norm[:,None]) @ Bt^T ----------------
template<int K, int N, bool A_F32>
__global__ __launch_bounds__(256) void mfma_gemm(const void* __restrict__ Aptr,
                                                 const float* __restrict__ norm,
                                                 const f16* __restrict__ Bt,
                                                 f16* __restrict__ H, int M) {
    constexpr int BM = 128, BN = 128, BK = 32;
    __shared__ __align__(16) f16 smem[BM * BN];     // 32KB; k-loop uses first 16KB
    f16* As = smem;                                  // [128][32] row-major
    f16* Bs = smem + BM * BK;                        // [128 cols][32], 16B-XOR-swizzled

    const int rbase = blockIdx.x * BM;
    const int nb = blockIdx.y * BN;
    const int tid = threadIdx.x;
    const int l = tid & 63, wid = tid >> 6;
    const int wr = wid >> 1, wc = wid & 1;
    const int fr = l & 15, kg = l >> 4;

    f32x4 acc[4][4] = {};

    for (int kt = 0; kt < K / BK; ++kt) {
        const int k0 = kt * BK;
        __syncthreads();
#pragma unroll
        for (int j = 0; j < 2; ++j) {
            int u = tid + j * 256;
            {   // A unit: 16B of one row
                int row = u >> 2, un = u & 3;
                int grow = rbase + row;
                f16x8 v = {};
                if (grow < M) {
                    if (A_F32) {
                        const float* A = (const float*)Aptr + (long)grow * K + k0 + un * 8;
                        float s = norm[grow];
                        float4 a0 = *(const float4*)A;
                        float4 a1 = *(const float4*)(A + 4);
                        v[0] = (f16)(a0.x * s); v[1] = (f16)(a0.y * s);
                        v[2] = (f16)(a0.z * s); v[3] = (f16)(a0.w * s);
                        v[4] = (f16)(a1.x * s); v[5] = (f16)(a1.y * s);
                        v[6] = (f16)(a1.z * s); v[7] = (f16)(a1.w * s);
                    } else {
                        v = *(const f16x8*)((const f16*)Aptr + (long)grow * K + k0 + un * 8);
                    }
                }
                *(f16x8*)&As[row * BK + un * 8] = v;
            }
            {   // B unit
                int c = u >> 2, un = u & 3;
                f16x8 v = *(const f16x8*)(Bt + (long)(nb + c) * K + k0 + un * 8);
                int idx = (c * BK + un * 8) ^ ((c & 7) << 3);
                *(f16x8*)&Bs[idx] = v;
            }
        }
        __syncthreads();

        f16x8 af[4], bf[4];
#pragma unroll
        for (int m = 0; m < 4; ++m)
            af[m] = *(const f16x8*)&As[(wr * 64 + m * 16 + fr) * BK + kg * 8];
#pragma unroll
        for (int nf = 0; nf < 4; ++nf) {
            int c = wc * 64 + nf * 16 + fr;
            int idx = (c * BK + kg * 8) ^ ((c & 7) << 3);
            bf[nf] = *(const f16x8*)&Bs[idx];
        }
#pragma unroll
        for (int m = 0; m < 4; ++m)
#pragma unroll
            for (int nf = 0; nf < 4; ++nf)
                acc[m][nf] = __builtin_amdgcn_mfma_f32_16x16x32_f16(af[m], bf[nf], acc[m][nf], 0, 0, 0);
    }

    __syncthreads();
    // restage C tile in LDS (f16) for coalesced stores
#pragma unroll
    for (int m = 0; m < 4; ++m)
#pragma unroll
        for (int nf = 0; nf < 4; ++nf)
#pragma unroll
            for (int i = 0; i < 4; ++i) {
                int row = wr * 64 + m * 16 + (l >> 4) * 4 + i;
                int col = wc * 64 + nf * 16 + (l & 15);
                smem[row * BN + col] = (f16)acc[m][nf][i];
            }
    __syncthreads();
#pragma unroll
    for (int j = 0; j < 8; ++j) {
        int u = tid + j * 256;
        int row = u >> 4, cu = u & 15;
        int grow = rbase + row;
        if (grow < M)
            *(f16x8*)(H + (long)grow * N + nb + cu * 8) =
                *(const f16x8*)&smem[row * BN + cu * 8];
    }
}

// ---------------- wave-per-node CSR aggregate, fused epilogue ----------------
// One 64-lane wave per dst node; lane owns VPL = F/64 contiguous f16 columns.
// Per edge, a lane loads f16x{VPL} (8B/4B) -> whole row covered by one wave instr.
// 4-deep edge unroll for memory-level parallelism.
template<int F, bool RELU, bool FOLD, bool OUT_F16>
__global__ __launch_bounds__(256) void aggregate_wave(const f16* __restrict__ H,
                                                      const int* __restrict__ rowptr,
                                                      const int* __restrict__ csr_src,
                                                      const float* __restrict__ norm_dst,
                                                      const float* __restrict__ norm_src,
                                                      const float* __restrict__ bias,
                                                      void* __restrict__ outp, int n) {
    constexpr int VPL = F / 64;                         // 4 for F=256, 2 for F=128
    using vec = typename std::conditional<VPL == 4, f16v4, f16v2>::type;

    const int node = blockIdx.x * 4 + (threadIdx.x >> 6);
    if (node >= n) return;
    const int l = threadIdx.x & 63;
    const int c0 = l * VPL;
    const f16* __restrict__ Hc = H + c0;

    int k = rowptr[node];
    const int end = rowptr[node + 1];

    float acc[VPL] = {};
    for (; k + 3 < end; k += 4) {
        int s0 = csr_src[k];
        int s1 = csr_src[k + 1];
        int s2 = csr_src[k + 2];
        int s3 = csr_src[k + 3];
        vec v0 = *(const vec*)(Hc + (long)s0 * F);
        vec v1 = *(const vec*)(Hc + (long)s1 * F);
        vec v2 = *(const vec*)(Hc + (long)s2 * F);
        vec v3 = *(const vec*)(Hc + (long)s3 * F);
#pragma unroll
        for (int q = 0; q < VPL; ++q) acc[q] += (float)v0[q];
#pragma unroll
        for (int q = 0; q < VPL; ++q) acc[q] += (float)v1[q];
#pragma unroll
        for (int q = 0; q < VPL; ++q) acc[q] += (float)v2[q];
#pragma unroll
        for (int q = 0; q < VPL; ++q) acc[q] += (float)v3[q];
    }
    for (; k < end; ++k) {
        vec v = *(const vec*)(Hc + (long)csr_src[k] * F);
#pragma unroll
        for (int q = 0; q < VPL; ++q) acc[q] += (float)v[q];
    }

    const float nd = norm_dst[node];
    const float ns = FOLD ? norm_src[node] : 1.0f;
#pragma unroll
    for (int q = 0; q < VPL; ++q) {
        float v = acc[q] * nd + bias[c0 + q];
        if (RELU) v = fmaxf(v, 0.0f);
        acc[q] = v * ns;
    }

    if (OUT_F16) {
        vec o;
#pragma unroll
        for (int q = 0; q < VPL; ++q) o[q] = (f16)acc[q];
        *(vec*)((f16*)outp + (long)node * F + c0) = o;
    } else {
        float* op = (float*)outp + (long)node * F + c0;
        if (VPL == 2) {
            *(float2*)op = make_float2(acc[0], acc[1]);
        } else {
#pragma unroll
            for (int q = 0; q < VPL; ++q) op[q] = acc[q];
        }
    }
}

extern "C" void kernel_launch(void* const* d_in, const int* in_sizes, int n_in,
                              void* d_out, int out_size, void* d_ws, size_t ws_size,
                              hipStream_t stream) {
    const float* features = (const float*)d_in[0];
    const int*   src      = (const int*)d_in[1];
    const int*   dst      = (const int*)d_in[2];
    const float* W1       = (const float*)d_in[3];
    const float* b1       = (const float*)d_in[4];
    const float* W2       = (const float*)d_in[5];
    const float* b2       = (const float*)d_in[6];
    float* out = (float*)d_out;

    const int n = in_sizes[0] / DIN;   // 50000
    const int e = in_sizes[1];         // 800000

    // ---- workspace layout ----
    char* ws = (char*)d_ws;
    size_t off = 0;
    auto alloc = [&](size_t bytes) { size_t o = off; off += (bytes + 255) & ~(size_t)255; return o; };
    size_t o_degi   = alloc((size_t)n * 4);            // deg_in  [memset 0]
    size_t o_dego   = alloc((size_t)n * 4);            // deg_out [memset 0]
    size_t o_cursor = alloc((size_t)n * 4);            // cursors [memset 0]
    size_t o_nsrc   = alloc((size_t)n * 4);            // norm_src
    size_t o_ndst   = alloc((size_t)n * 4);            // norm_dst
    size_t o_rowptr = alloc((size_t)(n + 1) * 4);      // rowptr
    size_t o_csr    = alloc((size_t)e * 4);            // csr_src
    size_t o_w1t    = alloc((size_t)DIN * DHID * 2);   // W1^T f16
    size_t o_w2t    = alloc((size_t)DHID * DOF * 2);   // W2^T f16
    size_t o_h1     = alloc((size_t)n * DHID * 2);     // h1 f16
    size_t o_x1     = alloc((size_t)n * DHID * 2);     // x1 f16 (pre-scaled by norm_src)
    size_t o_h2     = alloc((size_t)n * DOF * 2);      // h2 f16
    (void)ws_size;

    int*   deg_in   = (int*)(ws + o_degi);
    int*   deg_out  = (int*)(ws + o_dego);
    int*   cursor   = (int*)(ws + o_cursor);
    float* norm_src = (float*)(ws + o_nsrc);
    float* norm_dst = (float*)(ws + o_ndst);
    int*   rowptr   = (int*)(ws + o_rowptr);
    int*   csr_src  = (int*)(ws + o_csr);
    f16*   w1t      = (f16*)(ws + o_w1t);
    f16*   w2t      = (f16*)(ws + o_w2t);
    f16*   h1       = (f16*)(ws + o_h1);
    f16*   x1       = (f16*)(ws + o_x1);
    f16*   h2       = (f16*)(ws + o_h2);

    hipMemsetAsync(ws, 0, o_nsrc, stream);   // deg_in, deg_out, cursor

    // ---- graph preprocessing ----
    count_deg<<<(e + 255) / 256, 256, 0, stream>>>(src, dst, deg_out, deg_in, e);
    make_norm<<<(n + 255) / 256, 256, 0, stream>>>(deg_out, deg_in, norm_src, norm_dst, n);
    scan_rowptr<<<1, 1024, 0, stream>>>(deg_in, rowptr, n);
    fill_csr<<<(e + 255) / 256, 256, 0, stream>>>(src, dst, rowptr, cursor, csr_src, e);
    transpose_w<<<(DIN * DHID + DHID * DOF + 255) / 256, 256, 0, stream>>>(W1, W2, w1t, w2t);

    const int mtiles = (n + 127) / 128;      // 391
    const int ablocks = (n + 3) / 4;         // 4 nodes (waves) per 256-thr block

    // ---- layer 1 ----
    mfma_gemm<DIN, DHID, true><<<dim3(mtiles, DHID / 128), 256, 0, stream>>>(
        features, norm_src, w1t, h1, n);
    aggregate_wave<DHID, true, true, true><<<ablocks, 256, 0, stream>>>(
        h1, rowptr, csr_src, norm_dst, norm_src, b1, x1, n);

    // ---- layer 2 ----
    mfma_gemm<DHID, DOF, false><<<dim3(mtiles, DOF / 128), 256, 0, stream>>>(
        x1, nullptr, w2t, h2, n);
    aggregate_wave<DOF, false, false, false><<<ablocks, 256, 0, stream>>>(
        h2, rowptr, csr_src, norm_dst, norm_src, b2, out, n);
}

// Round 9
// 295.768 us; speedup vs baseline: 5.0543x; 1.2270x over previous
//
#include <hip/hip_runtime.h>
#include <type_traits>

#define DIN  512
#define DHID 256
#define DOF  128

typedef _Float16 f16;
typedef _Float16 f16x8 __attribute__((ext_vector_type(8)));
typedef _Float16 f16v4 __attribute__((ext_vector_type(4)));
typedef _Float16 f16v2 __attribute__((ext_vector_type(2)));
typedef float f32x4 __attribute__((ext_vector_type(4)));

// ---------------- degree counting (int) ----------------
__global__ void count_deg(const int* __restrict__ src, const int* __restrict__ dst,
                          int* __restrict__ deg_out, int* __restrict__ deg_in, int e) {
    int i = blockIdx.x * blockDim.x + threadIdx.x;
    if (i < e) {
        atomicAdd(&deg_out[src[i]], 1);
        atomicAdd(&deg_in[dst[i]], 1);
    }
}

__global__ void make_norm(const int* __restrict__ deg_out, const int* __restrict__ deg_in,
                          float* __restrict__ norm_src, float* __restrict__ norm_dst, int n) {
    int i = blockIdx.x * blockDim.x + threadIdx.x;
    if (i < n) {
        norm_src[i] = rsqrtf(fmaxf((float)deg_out[i], 1.0f));
        norm_dst[i] = rsqrtf(fmaxf((float)deg_in[i], 1.0f));
    }
}

// ---------------- two-level exclusive scan: deg_in -> rowptr[n+1] ----------------
// 1024 elements per block; supports n <= 64*1024 (partials fit one wave).
__global__ __launch_bounds__(256) void scan_part(const int* __restrict__ deg,
                                                 int* __restrict__ partial, int n) {
    const int base = blockIdx.x * 1024;
    const int tid = threadIdx.x;
    int v = 0;
#pragma unroll
    for (int j = 0; j < 4; ++j) {
        int i = base + tid * 4 + j;
        if (i < n) v += deg[i];
    }
    for (int o = 1; o < 64; o <<= 1) v += __shfl_xor(v, o);
    __shared__ int wsum[4];
    if ((tid & 63) == 0) wsum[tid >> 6] = v;
    __syncthreads();
    if (tid == 0) partial[blockIdx.x] = wsum[0] + wsum[1] + wsum[2] + wsum[3];
}

// one wave: exclusive-scan the block partials in place; write rowptr[n] = total
__global__ __launch_bounds__(64) void scan_offsets(int* __restrict__ partial, int nb,
                                                   int* __restrict__ rowptr, int n) {
    const int l = threadIdx.x;
    int orig = (l < nb) ? partial[l] : 0;
    int v = orig;
    for (int o = 1; o < 64; o <<= 1) {
        int u = __shfl_up(v, o);
        if (l >= o) v += u;
    }
    if (l < nb) partial[l] = v - orig;        // exclusive
    if (l == nb - 1) rowptr[n] = v;           // total edge count
}

__global__ __launch_bounds__(256) void scan_apply(const int* __restrict__ deg,
                                                  const int* __restrict__ partial,
                                                  int* __restrict__ rowptr, int n) {
    const int base = blockIdx.x * 1024;
    const int tid = threadIdx.x;
    int x[4]; int s = 0;
#pragma unroll
    for (int j = 0; j < 4; ++j) {
        int i = base + tid * 4 + j;
        x[j] = (i < n) ? deg[i] : 0;
        s += x[j];
    }
    const int l = tid & 63, w = tid >> 6;
    int inc = s;
    for (int o = 1; o < 64; o <<= 1) {
        int u = __shfl_up(inc, o);
        if (l >= o) inc += u;
    }
    __shared__ int wsum[4];
    if (l == 63) wsum[w] = inc;
    __syncthreads();
    int wbase = 0;
    for (int q = 0; q < w; ++q) wbase += wsum[q];
    int excl = partial[blockIdx.x] + wbase + (inc - s);
#pragma unroll
    for (int j = 0; j < 4; ++j) {
        int i = base + tid * 4 + j;
        if (i < n) rowptr[i] = excl;
        excl += x[j];
    }
}

// ---------------- bucket fill: csr_src sorted by dst ----------------
__global__ void fill_csr(const int* __restrict__ src, const int* __restrict__ dst,
                         const int* __restrict__ rowptr, int* __restrict__ cursor,
                         int* __restrict__ csr_src, int e) {
    int i = blockIdx.x * blockDim.x + threadIdx.x;
    if (i < e) {
        int d = dst[i];
        int p = atomicAdd(&cursor[d], 1);
        csr_src[rowptr[d] + p] = src[i];
    }
}

// ---------------- W -> f16 transposed: wt[c][k] = (f16)W[k][c] ----------------
__global__ void transpose_w(const float* __restrict__ W1, const float* __restrict__ W2,
                            f16* __restrict__ w1t, f16* __restrict__ w2t) {
    int t = blockIdx.x * blockDim.x + threadIdx.x;
    if (t < DIN * DHID) {
        int k = t / DHID, c = t % DHID;
        w1t[c * DIN + k] = (f16)W1[t];
    } else {
        int u = t - DIN * DHID;
        if (u < DHID * DOF) {
            int k = u / DOF, c = u % DOF;
            w2t[c * DHID + k] = (f16)W2[u];
        }
    }
}

// ---------------- MFMA GEMM: H[M][N](f16) = (A * norm[:,None]) @ Bt^T ----------------
template<int K, int N, bool A_F32>
__global__ __launch_bounds__(256) void mfma_gemm(const void* __restrict__ Aptr,
                                                 const float* __restrict__ norm,
                                                 const f16* __restrict__ Bt,
                                                 f16* __restrict__ H, int M) {
    constexpr int BM = 128, BN = 128, BK = 32;
    __shared__ __align__(16) f16 smem[BM * BN];     // 32KB; k-loop uses first 16KB
    f16* As = smem;                                  // [128][32] row-major
    f16* Bs = smem + BM * BK;                        // [128 cols][32], 16B-XOR-swizzled

    const int rbase = blockIdx.x * BM;
    const int nb = blockIdx.y * BN;
    const int tid = threadIdx.x;
    const int l = tid & 63, wid = tid >> 6;
    const int wr = wid >> 1, wc = wid & 1;
    const int fr = l & 15, kg = l >> 4;

    f32x4 acc[4][4] = {};

    for (int kt = 0; kt < K / BK; ++kt) {
        const int k0 = kt * BK;
        __syncthreads();
#pragma unroll
        for (int j = 0; j < 2; ++j) {
            int u = tid + j * 256;
            {   // A unit: 16B of one row
                int row = u >> 2, un = u & 3;
                int grow = rbase + row;
                f16x8 v = {};
                if (grow < M) {
                    if (A_F32) {
                        const float* A = (const float*)Aptr + (long)grow * K + k0 + un * 8;
                        float s = norm[grow];
                        float4 a0 = *(const float4*)A;
                        float4 a1 = *(const float4*)(A + 4);
                        v[0] = (f16)(a0.x * s); v[1] = (f16)(a0.y * s);
                        v[2] = (f16)(a0.z * s); v[3] = (f16)(a0.w * s);
                        v[4] = (f16)(a1.x * s); v[5] = (f16)(a1.y * s);
                        v[6] = (f16)(a1.z * s); v[7] = (f16)(a1.w * s);
                    } else {
                        v = *(const f16x8*)((const f16*)Aptr + (long)grow * K + k0 + un * 8);
                    }
                }
                *(f16x8*)&As[row * BK + un * 8] = v;
            }
            {   // B unit
                int c = u >> 2, un = u & 3;
                f16x8 v = *(const f16x8*)(Bt + (long)(nb + c) * K + k0 + un * 8);
                int idx = (c * BK + un * 8) ^ ((c & 7) << 3);
                *(f16x8*)&Bs[idx] = v;
            }
        }
        __syncthreads();

        f16x8 af[4], bf[4];
#pragma unroll
        for (int m = 0; m < 4; ++m)
            af[m] = *(const f16x8*)&As[(wr * 64 + m * 16 + fr) * BK + kg * 8];
#pragma unroll
        for (int nf = 0; nf < 4; ++nf) {
            int c = wc * 64 + nf * 16 + fr;
            int idx = (c * BK + kg * 8) ^ ((c & 7) << 3);
            bf[nf] = *(const f16x8*)&Bs[idx];
        }
#pragma unroll
        for (int m = 0; m < 4; ++m)
#pragma unroll
            for (int nf = 0; nf < 4; ++nf)
                acc[m][nf] = __builtin_amdgcn_mfma_f32_16x16x32_f16(af[m], bf[nf], acc[m][nf], 0, 0, 0);
    }

    __syncthreads();
    // restage C tile in LDS (f16) for coalesced stores
#pragma unroll
    for (int m = 0; m < 4; ++m)
#pragma unroll
        for (int nf = 0; nf < 4; ++nf)
#pragma unroll
            for (int i = 0; i < 4; ++i) {
                int row = wr * 64 + m * 16 + (l >> 4) * 4 + i;
                int col = wc * 64 + nf * 16 + (l & 15);
                smem[row * BN + col] = (f16)acc[m][nf][i];
            }
    __syncthreads();
#pragma unroll
    for (int j = 0; j < 8; ++j) {
        int u = tid + j * 256;
        int row = u >> 4, cu = u & 15;
        int grow = rbase + row;
        if (grow < M)
            *(f16x8*)(H + (long)grow * N + nb + cu * 8) =
                *(const f16x8*)&smem[row * BN + cu * 8];
    }
}

// ---------------- wave-per-node CSR aggregate, fused epilogue ----------------
template<int F, bool RELU, bool FOLD, bool OUT_F16>
__global__ __launch_bounds__(256) void aggregate_wave(const f16* __restrict__ H,
                                                      const int* __restrict__ rowptr,
                                                      const int* __restrict__ csr_src,
                                                      const float* __restrict__ norm_dst,
                                                      const float* __restrict__ norm_src,
                                                      const float* __restrict__ bias,
                                                      void* __restrict__ outp, int n) {
    constexpr int VPL = F / 64;                         // 4 for F=256, 2 for F=128
    using vec = typename std::conditional<VPL == 4, f16v4, f16v2>::type;

    const int node = blockIdx.x * 4 + (threadIdx.x >> 6);
    if (node >= n) return;
    const int l = threadIdx.x & 63;
    const int c0 = l * VPL;
    const f16* __restrict__ Hc = H + c0;

    int k = rowptr[node];
    const int end = rowptr[node + 1];

    float acc[VPL] = {};
    for (; k + 3 < end; k += 4) {
        int s0 = csr_src[k];
        int s1 = csr_src[k + 1];
        int s2 = csr_src[k + 2];
        int s3 = csr_src[k + 3];
        vec v0 = *(const vec*)(Hc + (long)s0 * F);
        vec v1 = *(const vec*)(Hc + (long)s1 * F);
        vec v2 = *(const vec*)(Hc + (long)s2 * F);
        vec v3 = *(const vec*)(Hc + (long)s3 * F);
#pragma unroll
        for (int q = 0; q < VPL; ++q) acc[q] += (float)v0[q];
#pragma unroll
        for (int q = 0; q < VPL; ++q) acc[q] += (float)v1[q];
#pragma unroll
        for (int q = 0; q < VPL; ++q) acc[q] += (float)v2[q];
#pragma unroll
        for (int q = 0; q < VPL; ++q) acc[q] += (float)v3[q];
    }
    for (; k < end; ++k) {
        vec v = *(const vec*)(Hc + (long)csr_src[k] * F);
#pragma unroll
        for (int q = 0; q < VPL; ++q) acc[q] += (float)v[q];
    }

    const float nd = norm_dst[node];
    const float ns = FOLD ? norm_src[node] : 1.0f;
#pragma unroll
    for (int q = 0; q < VPL; ++q) {
        float v = acc[q] * nd + bias[c0 + q];
        if (RELU) v = fmaxf(v, 0.0f);
        acc[q] = v * ns;
    }

    if (OUT_F16) {
        vec o;
#pragma unroll
        for (int q = 0; q < VPL; ++q) o[q] = (f16)acc[q];
        *(vec*)((f16*)outp + (long)node * F + c0) = o;
    } else {
        float* op = (float*)outp + (long)node * F + c0;
        if (VPL == 2) {
            *(float2*)op = make_float2(acc[0], acc[1]);
        } else {
#pragma unroll
            for (int q = 0; q < VPL; ++q) op[q] = acc[q];
        }
    }
}

extern "C" void kernel_launch(void* const* d_in, const int* in_sizes, int n_in,
                              void* d_out, int out_size, void* d_ws, size_t ws_size,
                              hipStream_t stream) {
    const float* features = (const float*)d_in[0];
    const int*   src      = (const int*)d_in[1];
    const int*   dst      = (const int*)d_in[2];
    const float* W1       = (const float*)d_in[3];
    const float* b1       = (const float*)d_in[4];
    const float* W2       = (const float*)d_in[5];
    const float* b2       = (const float*)d_in[6];
    float* out = (float*)d_out;

    const int n = in_sizes[0] / DIN;   // 50000
    const int e = in_sizes[1];         // 800000

    // ---- workspace layout ----
    char* ws = (char*)d_ws;
    size_t off = 0;
    auto alloc = [&](size_t bytes) { size_t o = off; off += (bytes + 255) & ~(size_t)255; return o; };
    size_t o_degi   = alloc((size_t)n * 4);            // deg_in  [memset 0]
    size_t o_dego   = alloc((size_t)n * 4);            // deg_out [memset 0]
    size_t o_cursor = alloc((size_t)n * 4);            // cursors [memset 0]
    size_t o_nsrc   = alloc((size_t)n * 4);            // norm_src
    size_t o_ndst   = alloc((size_t)n * 4);            // norm_dst
    size_t o_rowptr = alloc((size_t)(n + 1) * 4);      // rowptr
    size_t o_part   = alloc((size_t)64 * 4);           // scan partials
    size_t o_csr    = alloc((size_t)e * 4);            // csr_src
    size_t o_w1t    = alloc((size_t)DIN * DHID * 2);   // W1^T f16
    size_t o_w2t    = alloc((size_t)DHID * DOF * 2);   // W2^T f16
    size_t o_h1     = alloc((size_t)n * DHID * 2);     // h1 f16
    size_t o_x1     = alloc((size_t)n * DHID * 2);     // x1 f16 (pre-scaled by norm_src)
    size_t o_h2     = alloc((size_t)n * DOF * 2);      // h2 f16
    (void)ws_size;

    int*   deg_in   = (int*)(ws + o_degi);
    int*   deg_out  = (int*)(ws + o_dego);
    int*   cursor   = (int*)(ws + o_cursor);
    float* norm_src = (float*)(ws + o_nsrc);
    float* norm_dst = (float*)(ws + o_ndst);
    int*   rowptr   = (int*)(ws + o_rowptr);
    int*   partial  = (int*)(ws + o_part);
    int*   csr_src  = (int*)(ws + o_csr);
    f16*   w1t      = (f16*)(ws + o_w1t);
    f16*   w2t      = (f16*)(ws + o_w2t);
    f16*   h1       = (f16*)(ws + o_h1);
    f16*   x1       = (f16*)(ws + o_x1);
    f16*   h2       = (f16*)(ws + o_h2);

    hipMemsetAsync(ws, 0, o_nsrc, stream);   // deg_in, deg_out, cursor

    // ---- graph preprocessing ----
    count_deg<<<(e + 255) / 256, 256, 0, stream>>>(src, dst, deg_out, deg_in, e);
    make_norm<<<(n + 255) / 256, 256, 0, stream>>>(deg_out, deg_in, norm_src, norm_dst, n);
    const int nb = (n + 1023) / 1024;        // 49 blocks (<= 64)
    scan_part<<<nb, 256, 0, stream>>>(deg_in, partial, n);
    scan_offsets<<<1, 64, 0, stream>>>(partial, nb, rowptr, n);
    scan_apply<<<nb, 256, 0, stream>>>(deg_in, partial, rowptr, n);
    fill_csr<<<(e + 255) / 256, 256, 0, stream>>>(src, dst, rowptr, cursor, csr_src, e);
    transpose_w<<<(DIN * DHID + DHID * DOF + 255) / 256, 256, 0, stream>>>(W1, W2, w1t, w2t);

    const int mtiles = (n + 127) / 128;      // 391
    const int ablocks = (n + 3) / 4;         // 4 nodes (waves) per 256-thr block

    // ---- layer 1 ----
    mfma_gemm<DIN, DHID, true><<<dim3(mtiles, DHID / 128), 256, 0, stream>>>(
        features, norm_src, w1t, h1, n);
    aggregate_wave<DHID, true, true, true><<<ablocks, 256, 0, stream>>>(
        h1, rowptr, csr_src, norm_dst, norm_src, b1, x1, n);

    // ---- layer 2 ----
    mfma_gemm<DHID, DOF, false><<<dim3(mtiles, DOF / 128), 256, 0, stream>>>(
        x1, nullptr, w2t, h2, n);
    aggregate_wave<DOF, false, false, false><<<ablocks, 256, 0, stream>>>(
        h2, rowptr, csr_src, norm_dst, norm_src, b2, out, n);
}

// Round 10
// 274.647 us; speedup vs baseline: 5.4429x; 1.0769x over previous
//
#include <hip/hip_runtime.h>
#include <type_traits>

#define DIN  512
#define DHID 256
#define DOF  128

typedef _Float16 f16;
typedef _Float16 f16x8 __attribute__((ext_vector_type(8)));
typedef _Float16 f16v4 __attribute__((ext_vector_type(4)));
typedef _Float16 f16v2 __attribute__((ext_vector_type(2)));
typedef float f32x4 __attribute__((ext_vector_type(4)));

// ---------------- degree counting (int) ----------------
__global__ void count_deg(const int* __restrict__ src, const int* __restrict__ dst,
                          int* __restrict__ deg_out, int* __restrict__ deg_in, int e) {
    int i = blockIdx.x * blockDim.x + threadIdx.x;
    if (i < e) {
        atomicAdd(&deg_out[src[i]], 1);
        atomicAdd(&deg_in[dst[i]], 1);
    }
}

__global__ void make_norm(const int* __restrict__ deg_out, const int* __restrict__ deg_in,
                          float* __restrict__ norm_src, float* __restrict__ norm_dst, int n) {
    int i = blockIdx.x * blockDim.x + threadIdx.x;
    if (i < n) {
        norm_src[i] = rsqrtf(fmaxf((float)deg_out[i], 1.0f));
        norm_dst[i] = rsqrtf(fmaxf((float)deg_in[i], 1.0f));
    }
}

// ---------------- two-level exclusive scan: deg_in -> rowptr[n+1] ----------------
__global__ __launch_bounds__(256) void scan_part(const int* __restrict__ deg,
                                                 int* __restrict__ partial, int n) {
    const int base = blockIdx.x * 1024;
    const int tid = threadIdx.x;
    int v = 0;
#pragma unroll
    for (int j = 0; j < 4; ++j) {
        int i = base + tid * 4 + j;
        if (i < n) v += deg[i];
    }
    for (int o = 1; o < 64; o <<= 1) v += __shfl_xor(v, o);
    __shared__ int wsum[4];
    if ((tid & 63) == 0) wsum[tid >> 6] = v;
    __syncthreads();
    if (tid == 0) partial[blockIdx.x] = wsum[0] + wsum[1] + wsum[2] + wsum[3];
}

__global__ __launch_bounds__(64) void scan_offsets(int* __restrict__ partial, int nb,
                                                   int* __restrict__ rowptr, int n) {
    const int l = threadIdx.x;
    int orig = (l < nb) ? partial[l] : 0;
    int v = orig;
    for (int o = 1; o < 64; o <<= 1) {
        int u = __shfl_up(v, o);
        if (l >= o) v += u;
    }
    if (l < nb) partial[l] = v - orig;        // exclusive
    if (l == nb - 1) rowptr[n] = v;           // total edge count
}

__global__ __launch_bounds__(256) void scan_apply(const int* __restrict__ deg,
                                                  const int* __restrict__ partial,
                                                  int* __restrict__ rowptr, int n) {
    const int base = blockIdx.x * 1024;
    const int tid = threadIdx.x;
    int x[4]; int s = 0;
#pragma unroll
    for (int j = 0; j < 4; ++j) {
        int i = base + tid * 4 + j;
        x[j] = (i < n) ? deg[i] : 0;
        s += x[j];
    }
    const int l = tid & 63, w = tid >> 6;
    int inc = s;
    for (int o = 1; o < 64; o <<= 1) {
        int u = __shfl_up(inc, o);
        if (l >= o) inc += u;
    }
    __shared__ int wsum[4];
    if (l == 63) wsum[w] = inc;
    __syncthreads();
    int wbase = 0;
    for (int q = 0; q < w; ++q) wbase += wsum[q];
    int excl = partial[blockIdx.x] + wbase + (inc - s);
#pragma unroll
    for (int j = 0; j < 4; ++j) {
        int i = base + tid * 4 + j;
        if (i < n) rowptr[i] = excl;
        excl += x[j];
    }
}

// ---------------- bucket fill: csr_src sorted by dst ----------------
__global__ void fill_csr(const int* __restrict__ src, const int* __restrict__ dst,
                         const int* __restrict__ rowptr, int* __restrict__ cursor,
                         int* __restrict__ csr_src, int e) {
    int i = blockIdx.x * blockDim.x + threadIdx.x;
    if (i < e) {
        int d = dst[i];
        int p = atomicAdd(&cursor[d], 1);
        csr_src[rowptr[d] + p] = src[i];
    }
}

// ---------------- W -> f16 transposed: wt[c][k] = (f16)W[k][c] ----------------
__global__ void transpose_w(const float* __restrict__ W1, const float* __restrict__ W2,
                            f16* __restrict__ w1t, f16* __restrict__ w2t) {
    int t = blockIdx.x * blockDim.x + threadIdx.x;
    if (t < DIN * DHID) {
        int k = t / DHID, c = t % DHID;
        w1t[c * DIN + k] = (f16)W1[t];
    } else {
        int u = t - DIN * DHID;
        if (u < DHID * DOF) {
            int k = u / DOF, c = u % DOF;
            w2t[c * DHID + k] = (f16)W2[u];
        }
    }
}

// ---------------- MFMA GEMM, 2-deep-prefetch double-buffered ----------------
// H[M][N](f16) = (A * norm[:,None]) @ Bt^T.  A: f32 (A_F32) or f16.  Bt: f16 [N][K].
// Block 256 thr = 4 waves; BM=128, BN=128, BK=32; wave -> 64x64 (4x4 frags 16x16x32).
// LDS: two 16KB k-buffers (As 8KB + Bs 8KB each), XOR-swizzled both sides;
// epilogue aliases the 32KB for C restage.
template<int K, int N, bool A_F32>
__global__ __launch_bounds__(256) void mfma_gemm(const void* __restrict__ Aptr,
                                                 const float* __restrict__ norm,
                                                 const f16* __restrict__ Bt,
                                                 f16* __restrict__ H, int M) {
    constexpr int BM = 128, BN = 128, BK = 32;
    constexpr int NT = K / BK;                       // 16 (L1) / 8 (L2), even
    __shared__ __align__(16) f16 smem[BM * BN];      // 32KB total

    const int rbase = blockIdx.x * BM;
    const int nbj = blockIdx.y * BN;
    const int tid = threadIdx.x;
    const int l = tid & 63, wid = tid >> 6;
    const int wr = wid >> 1, wc = wid & 1;
    const int fr = l & 15, kg = l >> 4;

    // fixed per-thread staging coords: 2 A-chunks + 2 B-chunks of 16B (8 f16)
    int arow[2], achk[2];
    float ascale[2];
#pragma unroll
    for (int j = 0; j < 2; ++j) {
        int u = tid + j * 256;
        arow[j] = u >> 2; achk[j] = u & 3;
        if (A_F32) {
            int grow = rbase + arow[j];
            ascale[j] = (grow < M) ? norm[grow] : 0.0f;
        }
    }

    struct ABregs {
        float4 a0[2], a1[2];   // used when A_F32
        f16x8  a16[2];         // used when !A_F32
        f16x8  b[2];
    };

    auto gload = [&](int k0) {
        ABregs r;
#pragma unroll
        for (int j = 0; j < 2; ++j) {
            int grow = rbase + arow[j];
            if (A_F32) {
                if (grow < M) {
                    const float* A = (const float*)Aptr + (long)grow * K + k0 + achk[j] * 8;
                    r.a0[j] = *(const float4*)A;
                    r.a1[j] = *(const float4*)(A + 4);
                } else {
                    r.a0[j] = make_float4(0.f, 0.f, 0.f, 0.f);
                    r.a1[j] = make_float4(0.f, 0.f, 0.f, 0.f);
                }
            } else {
                f16x8 v = {};
                if (grow < M)
                    v = *(const f16x8*)((const f16*)Aptr + (long)grow * K + k0 + achk[j] * 8);
                r.a16[j] = v;
            }
            // B: cols always valid (N multiple of 128)
            r.b[j] = *(const f16x8*)(Bt + (long)(nbj + arow[j]) * K + k0 + achk[j] * 8);
        }
        return r;
    };

    auto swrite = [&](int buf, const ABregs& r) {
        f16* As = smem + buf * 8192;
        f16* Bs = As + 4096;
#pragma unroll
        for (int j = 0; j < 2; ++j) {
            f16x8 v;
            if (A_F32) {
                float s = ascale[j];
                v[0] = (f16)(r.a0[j].x * s); v[1] = (f16)(r.a0[j].y * s);
                v[2] = (f16)(r.a0[j].z * s); v[3] = (f16)(r.a0[j].w * s);
                v[4] = (f16)(r.a1[j].x * s); v[5] = (f16)(r.a1[j].y * s);
                v[6] = (f16)(r.a1[j].z * s); v[7] = (f16)(r.a1[j].w * s);
            } else {
                v = r.a16[j];
            }
            int ia = (arow[j] * BK + achk[j] * 8) ^ ((arow[j] & 7) << 3);
            *(f16x8*)&As[ia] = v;
            int ib = ia;       // same coords for B
            *(f16x8*)&Bs[ib] = r.b[j];
        }
    };

    f32x4 acc[4][4] = {};

    auto compute = [&](int buf) {
        const f16* As = smem + buf * 8192;
        const f16* Bs = As + 4096;
        f16x8 af[4], bf[4];
#pragma unroll
        for (int m = 0; m < 4; ++m) {
            int row = wr * 64 + m * 16 + fr;
            int ia = (row * BK + kg * 8) ^ ((row & 7) << 3);
            af[m] = *(const f16x8*)&As[ia];
        }
#pragma unroll
        for (int nf = 0; nf < 4; ++nf) {
            int c = wc * 64 + nf * 16 + fr;
            int ib = (c * BK + kg * 8) ^ ((c & 7) << 3);
            bf[nf] = *(const f16x8*)&Bs[ib];
        }
#pragma unroll
        for (int m = 0; m < 4; ++m)
#pragma unroll
            for (int nf = 0; nf < 4; ++nf)
                acc[m][nf] = __builtin_amdgcn_mfma_f32_16x16x32_f16(af[m], bf[nf], acc[m][nf], 0, 0, 0);
    };

    // prologue: tile 0 staged; tile 1 in flight
    ABregs ra = gload(0);
    swrite(0, ra);
    ABregs rb = gload(BK);

    // main loop: 2 K-steps per iteration, named reg sets (no runtime indexing)
#pragma unroll
    for (int kt = 0; kt < NT; kt += 2) {
        // even step: compute buf0, issue kt+2 -> ra, write rb -> buf1
        __syncthreads();
        if (kt + 2 < NT) ra = gload((kt + 2) * BK);
        compute(0);
        if (kt + 1 < NT) swrite(1, rb);
        // odd step: compute buf1, issue kt+3 -> rb, write ra -> buf0
        if (kt + 1 < NT) {
            __syncthreads();
            if (kt + 3 < NT) rb = gload((kt + 3) * BK);
            compute(1);
            if (kt + 2 < NT) swrite(0, ra);
        }
    }

    __syncthreads();
    // restage C tile in LDS (f16) for coalesced stores
#pragma unroll
    for (int m = 0; m < 4; ++m)
#pragma unroll
        for (int nf = 0; nf < 4; ++nf)
#pragma unroll
            for (int i = 0; i < 4; ++i) {
                int row = wr * 64 + m * 16 + (l >> 4) * 4 + i;
                int col = wc * 64 + nf * 16 + (l & 15);
                smem[row * BN + col] = (f16)acc[m][nf][i];
            }
    __syncthreads();
#pragma unroll
    for (int j = 0; j < 8; ++j) {
        int u = tid + j * 256;
        int row = u >> 4, cu = u & 15;
        int grow = rbase + row;
        if (grow < M)
            *(f16x8*)(H + (long)grow * N + nbj + cu * 8) =
                *(const f16x8*)&smem[row * BN + cu * 8];
    }
}

// ---------------- wave-per-node CSR aggregate, fused epilogue ----------------
template<int F, bool RELU, bool FOLD, bool OUT_F16>
__global__ __launch_bounds__(256) void aggregate_wave(const f16* __restrict__ H,
                                                      const int* __restrict__ rowptr,
                                                      const int* __restrict__ csr_src,
                                                      const float* __restrict__ norm_dst,
                                                      const float* __restrict__ norm_src,
                                                      const float* __restrict__ bias,
                                                      void* __restrict__ outp, int n) {
    constexpr int VPL = F / 64;                         // 4 for F=256, 2 for F=128
    using vec = typename std::conditional<VPL == 4, f16v4, f16v2>::type;

    const int node = blockIdx.x * 4 + (threadIdx.x >> 6);
    if (node >= n) return;
    const int l = threadIdx.x & 63;
    const int c0 = l * VPL;
    const f16* __restrict__ Hc = H + c0;

    int k = rowptr[node];
    const int end = rowptr[node + 1];

    float acc[VPL] = {};
    for (; k + 3 < end; k += 4) {
        int s0 = csr_src[k];
        int s1 = csr_src[k + 1];
        int s2 = csr_src[k + 2];
        int s3 = csr_src[k + 3];
        vec v0 = *(const vec*)(Hc + (long)s0 * F);
        vec v1 = *(const vec*)(Hc + (long)s1 * F);
        vec v2 = *(const vec*)(Hc + (long)s2 * F);
        vec v3 = *(const vec*)(Hc + (long)s3 * F);
#pragma unroll
        for (int q = 0; q < VPL; ++q) acc[q] += (float)v0[q];
#pragma unroll
        for (int q = 0; q < VPL; ++q) acc[q] += (float)v1[q];
#pragma unroll
        for (int q = 0; q < VPL; ++q) acc[q] += (float)v2[q];
#pragma unroll
        for (int q = 0; q < VPL; ++q) acc[q] += (float)v3[q];
    }
    for (; k < end; ++k) {
        vec v = *(const vec*)(Hc + (long)csr_src[k] * F);
#pragma unroll
        for (int q = 0; q < VPL; ++q) acc[q] += (float)v[q];
    }

    const float nd = norm_dst[node];
    const float ns = FOLD ? norm_src[node] : 1.0f;
#pragma unroll
    for (int q = 0; q < VPL; ++q) {
        float v = acc[q] * nd + bias[c0 + q];
        if (RELU) v = fmaxf(v, 0.0f);
        acc[q] = v * ns;
    }

    if (OUT_F16) {
        vec o;
#pragma unroll
        for (int q = 0; q < VPL; ++q) o[q] = (f16)acc[q];
        *(vec*)((f16*)outp + (long)node * F + c0) = o;
    } else {
        float* op = (float*)outp + (long)node * F + c0;
        if (VPL == 2) {
            *(float2*)op = make_float2(acc[0], acc[1]);
        } else {
#pragma unroll
            for (int q = 0; q < VPL; ++q) op[q] = acc[q];
        }
    }
}

extern "C" void kernel_launch(void* const* d_in, const int* in_sizes, int n_in,
                              void* d_out, int out_size, void* d_ws, size_t ws_size,
                              hipStream_t stream) {
    const float* features = (const float*)d_in[0];
    const int*   src      = (const int*)d_in[1];
    const int*   dst      = (const int*)d_in[2];
    const float* W1       = (const float*)d_in[3];
    const float* b1       = (const float*)d_in[4];
    const float* W2       = (const float*)d_in[5];
    const float* b2       = (const float*)d_in[6];
    float* out = (float*)d_out;

    const int n = in_sizes[0] / DIN;   // 50000
    const int e = in_sizes[1];         // 800000

    // ---- workspace layout ----
    char* ws = (char*)d_ws;
    size_t off = 0;
    auto alloc = [&](size_t bytes) { size_t o = off; off += (bytes + 255) & ~(size_t)255; return o; };
    size_t o_degi   = alloc((size_t)n * 4);            // deg_in  [memset 0]
    size_t o_dego   = alloc((size_t)n * 4);            // deg_out [memset 0]
    size_t o_cursor = alloc((size_t)n * 4);            // cursors [memset 0]
    size_t o_nsrc   = alloc((size_t)n * 4);            // norm_src
    size_t o_ndst   = alloc((size_t)n * 4);            // norm_dst
    size_t o_rowptr = alloc((size_t)(n + 1) * 4);      // rowptr
    size_t o_part   = alloc((size_t)64 * 4);           // scan partials
    size_t o_csr    = alloc((size_t)e * 4);            // csr_src
    size_t o_w1t    = alloc((size_t)DIN * DHID * 2);   // W1^T f16
    size_t o_w2t    = alloc((size_t)DHID * DOF * 2);   // W2^T f16
    size_t o_h1     = alloc((size_t)n * DHID * 2);     // h1 f16
    size_t o_x1     = alloc((size_t)n * DHID * 2);     // x1 f16 (pre-scaled by norm_src)
    size_t o_h2     = alloc((size_t)n * DOF * 2);      // h2 f16
    (void)ws_size;

    int*   deg_in   = (int*)(ws + o_degi);
    int*   deg_out  = (int*)(ws + o_dego);
    int*   cursor   = (int*)(ws + o_cursor);
    float* norm_src = (float*)(ws + o_nsrc);
    float* norm_dst = (float*)(ws + o_ndst);
    int*   rowptr   = (int*)(ws + o_rowptr);
    int*   partial  = (int*)(ws + o_part);
    int*   csr_src  = (int*)(ws + o_csr);
    f16*   w1t      = (f16*)(ws + o_w1t);
    f16*   w2t      = (f16*)(ws + o_w2t);
    f16*   h1       = (f16*)(ws + o_h1);
    f16*   x1       = (f16*)(ws + o_x1);
    f16*   h2       = (f16*)(ws + o_h2);

    hipMemsetAsync(ws, 0, o_nsrc, stream);   // deg_in, deg_out, cursor

    // ---- graph preprocessing ----
    count_deg<<<(e + 255) / 256, 256, 0, stream>>>(src, dst, deg_out, deg_in, e);
    make_norm<<<(n + 255) / 256, 256, 0, stream>>>(deg_out, deg_in, norm_src, norm_dst, n);
    const int nb = (n + 1023) / 1024;        // 49 blocks (<= 64)
    scan_part<<<nb, 256, 0, stream>>>(deg_in, partial, n);
    scan_offsets<<<1, 64, 0, stream>>>(partial, nb, rowptr, n);
    scan_apply<<<nb, 256, 0, stream>>>(deg_in, partial, rowptr, n);
    fill_csr<<<(e + 255) / 256, 256, 0, stream>>>(src, dst, rowptr, cursor, csr_src, e);
    transpose_w<<<(DIN * DHID + DHID * DOF + 255) / 256, 256, 0, stream>>>(W1, W2, w1t, w2t);

    const int mtiles = (n + 127) / 128;      // 391
    const int ablocks = (n + 3) / 4;         // 4 nodes (waves) per 256-thr block

    // ---- layer 1 ----
    mfma_gemm<DIN, DHID, true><<<dim3(mtiles, DHID / 128), 256, 0, stream>>>(
        features, norm_src, w1t, h1, n);
    aggregate_wave<DHID, true, true, true><<<ablocks, 256, 0, stream>>>(
        h1, rowptr, csr_src, norm_dst, norm_src, b1, x1, n);

    // ---- layer 2 ----
    mfma_gemm<DHID, DOF, false><<<dim3(mtiles, DOF / 128), 256, 0, stream>>>(
        x1, nullptr, w2t, h2, n);
    aggregate_wave<DOF, false, false, false><<<ablocks, 256, 0, stream>>>(
        h2, rowptr, csr_src, norm_dst, norm_src, b2, out, n);
}

// Round 12
// 218.099 us; speedup vs baseline: 6.8542x; 1.2593x over previous
//
#include <hip/hip_runtime.h>
#include <type_traits>

#define DIN  512
#define DHID 256
#define DOF  128

// CSR-build partitioning: node ranges of 8192, 32 blocks share each range's edges
#define RB   13
#define RSZ  (1 << RB)      // 8192 nodes per range
#define BPR  32             // blocks per range

typedef _Float16 f16;
typedef _Float16 f16x8 __attribute__((ext_vector_type(8)));
typedef _Float16 f16v4 __attribute__((ext_vector_type(4)));
typedef _Float16 f16v2 __attribute__((ext_vector_type(2)));
typedef float f32x4 __attribute__((ext_vector_type(4)));

// ---------------- per-(range,block) LDS histograms of src/dst ----------------
// block (r,b): LDS-count nodes in [r*8192,(r+1)*8192) over edge chunk b,
// then write counts with plain coalesced stores (NO global atomics).
__global__ __launch_bounds__(256) void hist_deg(const int* __restrict__ src,
                                                const int* __restrict__ dst, int e,
                                                int* __restrict__ cnt_out,
                                                int* __restrict__ cnt_in) {
    __shared__ int h_out[RSZ], h_in[RSZ];
    const int r = blockIdx.x / BPR, b = blockIdx.x % BPR;
    const int base = r << RB;
    const int tid = threadIdx.x;
    for (int j = tid; j < RSZ; j += 256) { h_out[j] = 0; h_in[j] = 0; }
    __syncthreads();

    const int ce = (((e + BPR - 1) / BPR) + 3) & ~3;
    const int s0 = b * ce, s1 = min(s0 + ce, e);
    for (int i = s0 + tid * 4; i < s1; i += 1024) {
        if (i + 3 < s1) {
            int4 sv = *(const int4*)(src + i);
            int4 dv = *(const int4*)(dst + i);
            int v;
            v = sv.x - base; if ((unsigned)v < RSZ) atomicAdd(&h_out[v], 1);
            v = sv.y - base; if ((unsigned)v < RSZ) atomicAdd(&h_out[v], 1);
            v = sv.z - base; if ((unsigned)v < RSZ) atomicAdd(&h_out[v], 1);
            v = sv.w - base; if ((unsigned)v < RSZ) atomicAdd(&h_out[v], 1);
            v = dv.x - base; if ((unsigned)v < RSZ) atomicAdd(&h_in[v], 1);
            v = dv.y - base; if ((unsigned)v < RSZ) atomicAdd(&h_in[v], 1);
            v = dv.z - base; if ((unsigned)v < RSZ) atomicAdd(&h_in[v], 1);
            v = dv.w - base; if ((unsigned)v < RSZ) atomicAdd(&h_in[v], 1);
        } else {
            for (int q = i; q < s1; ++q) {
                int v = src[q] - base; if ((unsigned)v < RSZ) atomicAdd(&h_out[v], 1);
                v = dst[q] - base;     if ((unsigned)v < RSZ) atomicAdd(&h_in[v], 1);
            }
        }
    }
    __syncthreads();
    int* co = cnt_out + (size_t)(r * BPR + b) * RSZ;
    int* ci = cnt_in  + (size_t)(r * BPR + b) * RSZ;
    for (int j = tid; j < RSZ; j += 256) { co[j] = h_out[j]; ci[j] = h_in[j]; }
}

// ---------------- per-node: sum counts -> deg/norms; exclusive-scan cnt_in over b ----------------
__global__ void sum_base(const int* __restrict__ cnt_out, int* __restrict__ cnt_in,
                         int* __restrict__ deg_in,
                         float* __restrict__ norm_src, float* __restrict__ norm_dst, int n) {
    int d = blockIdx.x * blockDim.x + threadIdx.x;
    if (d >= n) return;
    const int r = d >> RB, j = d & (RSZ - 1);
    int* ci = cnt_in + (size_t)(r * BPR) * RSZ + j;
    int s = 0;
#pragma unroll 4
    for (int b = 0; b < BPR; ++b) {
        int c = ci[(size_t)b * RSZ];
        ci[(size_t)b * RSZ] = s;          // in-place exclusive base
        s += c;
    }
    deg_in[d] = s;
    norm_dst[d] = rsqrtf(fmaxf((float)s, 1.0f));
    const int* co = cnt_out + (size_t)(r * BPR) * RSZ + j;
    int s2 = 0;
#pragma unroll 4
    for (int b = 0; b < BPR; ++b) s2 += co[(size_t)b * RSZ];
    norm_src[d] = rsqrtf(fmaxf((float)s2, 1.0f));
}

// ---------------- two-level exclusive scan: deg_in -> rowptr[n+1] ----------------
__global__ __launch_bounds__(256) void scan_part(const int* __restrict__ deg,
                                                 int* __restrict__ partial, int n) {
    const int base = blockIdx.x * 1024;
    const int tid = threadIdx.x;
    int v = 0;
#pragma unroll
    for (int j = 0; j < 4; ++j) {
        int i = base + tid * 4 + j;
        if (i < n) v += deg[i];
    }
    for (int o = 1; o < 64; o <<= 1) v += __shfl_xor(v, o);
    __shared__ int wsum[4];
    if ((tid & 63) == 0) wsum[tid >> 6] = v;
    __syncthreads();
    if (tid == 0) partial[blockIdx.x] = wsum[0] + wsum[1] + wsum[2] + wsum[3];
}

__global__ __launch_bounds__(64) void scan_offsets(int* __restrict__ partial, int nb,
                                                   int* __restrict__ rowptr, int n) {
    const int l = threadIdx.x;
    int orig = (l < nb) ? partial[l] : 0;
    int v = orig;
    for (int o = 1; o < 64; o <<= 1) {
        int u = __shfl_up(v, o);
        if (l >= o) v += u;
    }
    if (l < nb) partial[l] = v - orig;        // exclusive
    if (l == nb - 1) rowptr[n] = v;           // total edge count
}

__global__ __launch_bounds__(256) void scan_apply(const int* __restrict__ deg,
                                                  const int* __restrict__ partial,
                                                  int* __restrict__ rowptr, int n) {
    const int base = blockIdx.x * 1024;
    const int tid = threadIdx.x;
    int x[4]; int s = 0;
#pragma unroll
    for (int j = 0; j < 4; ++j) {
        int i = base + tid * 4 + j;
        x[j] = (i < n) ? deg[i] : 0;
        s += x[j];
    }
    const int l = tid & 63, w = tid >> 6;
    int inc = s;
    for (int o = 1; o < 64; o <<= 1) {
        int u = __shfl_up(inc, o);
        if (l >= o) inc += u;
    }
    __shared__ int wsum[4];
    if (l == 63) wsum[w] = inc;
    __syncthreads();
    int wbase = 0;
    for (int q = 0; q < w; ++q) wbase += wsum[q];
    int excl = partial[blockIdx.x] + wbase + (inc - s);
#pragma unroll
    for (int j = 0; j < 4; ++j) {
        int i = base + tid * 4 + j;
        if (i < n) rowptr[i] = excl;
        excl += x[j];
    }
}

// ---------------- fill csr_src: LDS cursors only, no global atomics ----------------
// Same (range, chunk) mapping as hist_deg; slot = rowptr[d] + base[b][d] + cursor++.
__global__ __launch_bounds__(256) void fill_csr2(const int* __restrict__ src,
                                                 const int* __restrict__ dst, int e,
                                                 const int* __restrict__ rowptr,
                                                 const int* __restrict__ base_in,
                                                 int* __restrict__ csr_src) {
    __shared__ int cur[RSZ];
    const int r = blockIdx.x / BPR, b = blockIdx.x % BPR;
    const int base = r << RB;
    const int tid = threadIdx.x;
    for (int j = tid; j < RSZ; j += 256) cur[j] = 0;
    __syncthreads();

    const int* bi = base_in + (size_t)(r * BPR + b) * RSZ;
    const int ce = (((e + BPR - 1) / BPR) + 3) & ~3;
    const int s0 = b * ce, s1 = min(s0 + ce, e);
    for (int i = s0 + tid * 4; i < s1; i += 1024) {
        if (i + 3 < s1) {
            int4 dv = *(const int4*)(dst + i);
            int4 sv = *(const int4*)(src + i);
            int v;
            v = dv.x - base; if ((unsigned)v < RSZ) { int p = atomicAdd(&cur[v], 1); csr_src[rowptr[base + v] + bi[v] + p] = sv.x; }
            v = dv.y - base; if ((unsigned)v < RSZ) { int p = atomicAdd(&cur[v], 1); csr_src[rowptr[base + v] + bi[v] + p] = sv.y; }
            v = dv.z - base; if ((unsigned)v < RSZ) { int p = atomicAdd(&cur[v], 1); csr_src[rowptr[base + v] + bi[v] + p] = sv.z; }
            v = dv.w - base; if ((unsigned)v < RSZ) { int p = atomicAdd(&cur[v], 1); csr_src[rowptr[base + v] + bi[v] + p] = sv.w; }
        } else {
            for (int q = i; q < s1; ++q) {
                int v = dst[q] - base;
                if ((unsigned)v < RSZ) { int p = atomicAdd(&cur[v], 1); csr_src[rowptr[base + v] + bi[v] + p] = src[q]; }
            }
        }
    }
}

// ---------------- W -> f16 transposed: wt[c][k] = (f16)W[k][c] ----------------
__global__ void transpose_w(const float* __restrict__ W1, const float* __restrict__ W2,
                            f16* __restrict__ w1t, f16* __restrict__ w2t) {
    int t = blockIdx.x * blockDim.x + threadIdx.x;
    if (t < DIN * DHID) {
        int k = t / DHID, c = t % DHID;
        w1t[c * DIN + k] = (f16)W1[t];
    } else {
        int u = t - DIN * DHID;
        if (u < DHID * DOF) {
            int k = u / DOF, c = u % DOF;
            w2t[c * DHID + k] = (f16)W2[u];
        }
    }
}

// ---------------- MFMA GEMM, 2-deep-prefetch double-buffered ----------------
template<int K, int N, bool A_F32>
__global__ __launch_bounds__(256) void mfma_gemm(const void* __restrict__ Aptr,
                                                 const float* __restrict__ norm,
                                                 const f16* __restrict__ Bt,
                                                 f16* __restrict__ H, int M) {
    constexpr int BM = 128, BN = 128, BK = 32;
    constexpr int NT = K / BK;                       // 16 (L1) / 8 (L2), even
    __shared__ __align__(16) f16 smem[BM * BN];      // 32KB total

    const int rbase = blockIdx.x * BM;
    const int nbj = blockIdx.y * BN;
    const int tid = threadIdx.x;
    const int l = tid & 63, wid = tid >> 6;
    const int wr = wid >> 1, wc = wid & 1;
    const int fr = l & 15, kg = l >> 4;

    int arow[2], achk[2];
    float ascale[2];
#pragma unroll
    for (int j = 0; j < 2; ++j) {
        int u = tid + j * 256;
        arow[j] = u >> 2; achk[j] = u & 3;
        if (A_F32) {
            int grow = rbase + arow[j];
            ascale[j] = (grow < M) ? norm[grow] : 0.0f;
        }
    }

    struct ABregs {
        float4 a0[2], a1[2];
        f16x8  a16[2];
        f16x8  b[2];
    };

    auto gload = [&](int k0) {
        ABregs r;
#pragma unroll
        for (int j = 0; j < 2; ++j) {
            int grow = rbase + arow[j];
            if (A_F32) {
                if (grow < M) {
                    const float* A = (const float*)Aptr + (long)grow * K + k0 + achk[j] * 8;
                    r.a0[j] = *(const float4*)A;
                    r.a1[j] = *(const float4*)(A + 4);
                } else {
                    r.a0[j] = make_float4(0.f, 0.f, 0.f, 0.f);
                    r.a1[j] = make_float4(0.f, 0.f, 0.f, 0.f);
                }
            } else {
                f16x8 v = {};
                if (grow < M)
                    v = *(const f16x8*)((const f16*)Aptr + (long)grow * K + k0 + achk[j] * 8);
                r.a16[j] = v;
            }
            r.b[j] = *(const f16x8*)(Bt + (long)(nbj + arow[j]) * K + k0 + achk[j] * 8);
        }
        return r;
    };

    auto swrite = [&](int buf, const ABregs& r) {
        f16* As = smem + buf * 8192;
        f16* Bs = As + 4096;
#pragma unroll
        for (int j = 0; j < 2; ++j) {
            f16x8 v;
            if (A_F32) {
                float s = ascale[j];
                v[0] = (f16)(r.a0[j].x * s); v[1] = (f16)(r.a0[j].y * s);
                v[2] = (f16)(r.a0[j].z * s); v[3] = (f16)(r.a0[j].w * s);
                v[4] = (f16)(r.a1[j].x * s); v[5] = (f16)(r.a1[j].y * s);
                v[6] = (f16)(r.a1[j].z * s); v[7] = (f16)(r.a1[j].w * s);
            } else {
                v = r.a16[j];
            }
            int ia = (arow[j] * BK + achk[j] * 8) ^ ((arow[j] & 7) << 3);
            *(f16x8*)&As[ia] = v;
            *(f16x8*)&Bs[ia] = r.b[j];
        }
    };

    f32x4 acc[4][4] = {};

    auto compute = [&](int buf) {
        const f16* As = smem + buf * 8192;
        const f16* Bs = As + 4096;
        f16x8 af[4], bf[4];
#pragma unroll
        for (int m = 0; m < 4; ++m) {
            int row = wr * 64 + m * 16 + fr;
            int ia = (row * BK + kg * 8) ^ ((row & 7) << 3);
            af[m] = *(const f16x8*)&As[ia];
        }
#pragma unroll
        for (int nf = 0; nf < 4; ++nf) {
            int c = wc * 64 + nf * 16 + fr;
            int ib = (c * BK + kg * 8) ^ ((c & 7) << 3);
            bf[nf] = *(const f16x8*)&Bs[ib];
        }
#pragma unroll
        for (int m = 0; m < 4; ++m)
#pragma unroll
            for (int nf = 0; nf < 4; ++nf)
                acc[m][nf] = __builtin_amdgcn_mfma_f32_16x16x32_f16(af[m], bf[nf], acc[m][nf], 0, 0, 0);
    };

    ABregs ra = gload(0);
    swrite(0, ra);
    ABregs rb = gload(BK);

#pragma unroll
    for (int kt = 0; kt < NT; kt += 2) {
        __syncthreads();
        if (kt + 2 < NT) ra = gload((kt + 2) * BK);
        compute(0);
        if (kt + 1 < NT) swrite(1, rb);
        if (kt + 1 < NT) {
            __syncthreads();
            if (kt + 3 < NT) rb = gload((kt + 3) * BK);
            compute(1);
            if (kt + 2 < NT) swrite(0, ra);
        }
    }

    __syncthreads();
#pragma unroll
    for (int m = 0; m < 4; ++m)
#pragma unroll
        for (int nf = 0; nf < 4; ++nf)
#pragma unroll
            for (int i = 0; i < 4; ++i) {
                int row = wr * 64 + m * 16 + (l >> 4) * 4 + i;
                int col = wc * 64 + nf * 16 + (l & 15);
                smem[row * BN + col] = (f16)acc[m][nf][i];
            }
    __syncthreads();
#pragma unroll
    for (int j = 0; j < 8; ++j) {
        int u = tid + j * 256;
        int row = u >> 4, cu = u & 15;
        int grow = rbase + row;
        if (grow < M)
            *(f16x8*)(H + (long)grow * N + nbj + cu * 8) =
                *(const f16x8*)&smem[row * BN + cu * 8];
    }
}

// ---------------- wave-per-node CSR aggregate, fused epilogue ----------------
template<int F, bool RELU, bool FOLD, bool OUT_F16>
__global__ __launch_bounds__(256) void aggregate_wave(const f16* __restrict__ H,
                                                      const int* __restrict__ rowptr,
                                                      const int* __restrict__ csr_src,
                                                      const float* __restrict__ norm_dst,
                                                      const float* __restrict__ norm_src,
                                                      const float* __restrict__ bias,
                                                      void* __restrict__ outp, int n) {
    constexpr int VPL = F / 64;
    using vec = typename std::conditional<VPL == 4, f16v4, f16v2>::type;

    const int node = blockIdx.x * 4 + (threadIdx.x >> 6);
    if (node >= n) return;
    const int l = threadIdx.x & 63;
    const int c0 = l * VPL;
    const f16* __restrict__ Hc = H + c0;

    int k = rowptr[node];
    const int end = rowptr[node + 1];

    float acc[VPL] = {};
    for (; k + 3 < end; k += 4) {
        int s0 = csr_src[k];
        int s1 = csr_src[k + 1];
        int s2 = csr_src[k + 2];
        int s3 = csr_src[k + 3];
        vec v0 = *(const vec*)(Hc + (long)s0 * F);
        vec v1 = *(const vec*)(Hc + (long)s1 * F);
        vec v2 = *(const vec*)(Hc + (long)s2 * F);
        vec v3 = *(const vec*)(Hc + (long)s3 * F);
#pragma unroll
        for (int q = 0; q < VPL; ++q) acc[q] += (float)v0[q];
#pragma unroll
        for (int q = 0; q < VPL; ++q) acc[q] += (float)v1[q];
#pragma unroll
        for (int q = 0; q < VPL; ++q) acc[q] += (float)v2[q];
#pragma unroll
        for (int q = 0; q < VPL; ++q) acc[q] += (float)v3[q];
    }
    for (; k < end; ++k) {
        vec v = *(const vec*)(Hc + (long)csr_src[k] * F);
#pragma unroll
        for (int q = 0; q < VPL; ++q) acc[q] += (float)v[q];
    }

    const float nd = norm_dst[node];
    const float ns = FOLD ? norm_src[node] : 1.0f;
#pragma unroll
    for (int q = 0; q < VPL; ++q) {
        float v = acc[q] * nd + bias[c0 + q];
        if (RELU) v = fmaxf(v, 0.0f);
        acc[q] = v * ns;
    }

    if (OUT_F16) {
        vec o;
#pragma unroll
        for (int q = 0; q < VPL; ++q) o[q] = (f16)acc[q];
        *(vec*)((f16*)outp + (long)node * F + c0) = o;
    } else {
        float* op = (float*)outp + (long)node * F + c0;
        if (VPL == 2) {
            *(float2*)op = make_float2(acc[0], acc[1]);
        } else {
#pragma unroll
            for (int q = 0; q < VPL; ++q) op[q] = acc[q];
        }
    }
}

extern "C" void kernel_launch(void* const* d_in, const int* in_sizes, int n_in,
                              void* d_out, int out_size, void* d_ws, size_t ws_size,
                              hipStream_t stream) {
    const float* features = (const float*)d_in[0];
    const int*   src      = (const int*)d_in[1];
    const int*   dst      = (const int*)d_in[2];
    const float* W1       = (const float*)d_in[3];
    const float* b1       = (const float*)d_in[4];
    const float* W2       = (const float*)d_in[5];
    const float* b2       = (const float*)d_in[6];
    float* out = (float*)d_out;

    const int n = in_sizes[0] / DIN;   // 50000
    const int e = in_sizes[1];         // 800000

    const int ranges = (n + RSZ - 1) >> RB;            // 7 for n=50000
    const size_t cntsz = (size_t)ranges * BPR * RSZ;   // ints per cnt array

    // ---- workspace layout ----
    char* ws = (char*)d_ws;
    size_t off = 0;
    auto alloc = [&](size_t bytes) { size_t o = off; off += (bytes + 255) & ~(size_t)255; return o; };
    size_t o_degi   = alloc((size_t)n * 4);            // deg_in (written by sum_base)
    size_t o_nsrc   = alloc((size_t)n * 4);            // norm_src
    size_t o_ndst   = alloc((size_t)n * 4);            // norm_dst
    size_t o_rowptr = alloc((size_t)(n + 1) * 4);      // rowptr
    size_t o_part   = alloc((size_t)64 * 4);           // scan partials
    size_t o_csr    = alloc((size_t)e * 4);            // csr_src
    size_t o_cnto   = alloc(cntsz * 4);                // cnt_out
    size_t o_cnti   = alloc(cntsz * 4);                // cnt_in -> base_in (in place)
    size_t o_w1t    = alloc((size_t)DIN * DHID * 2);   // W1^T f16
    size_t o_w2t    = alloc((size_t)DHID * DOF * 2);   // W2^T f16
    size_t o_h1     = alloc((size_t)n * DHID * 2);     // h1 f16
    size_t o_x1     = alloc((size_t)n * DHID * 2);     // x1 f16 (pre-scaled by norm_src)
    size_t o_h2     = alloc((size_t)n * DOF * 2);      // h2 f16
    (void)ws_size;

    int*   deg_in   = (int*)(ws + o_degi);
    float* norm_src = (float*)(ws + o_nsrc);
    float* norm_dst = (float*)(ws + o_ndst);
    int*   rowptr   = (int*)(ws + o_rowptr);
    int*   partial  = (int*)(ws + o_part);
    int*   csr_src  = (int*)(ws + o_csr);
    int*   cnt_out  = (int*)(ws + o_cnto);
    int*   cnt_in   = (int*)(ws + o_cnti);
    f16*   w1t      = (f16*)(ws + o_w1t);
    f16*   w2t      = (f16*)(ws + o_w2t);
    f16*   h1       = (f16*)(ws + o_h1);
    f16*   x1       = (f16*)(ws + o_x1);
    f16*   h2       = (f16*)(ws + o_h2);

    // ---- graph preprocessing (no global atomics, no memsets) ----
    const int hblocks = ranges * BPR;                  // 224
    hist_deg<<<hblocks, 256, 0, stream>>>(src, dst, e, cnt_out, cnt_in);
    sum_base<<<(n + 255) / 256, 256, 0, stream>>>(cnt_out, cnt_in, deg_in,
                                                  norm_src, norm_dst, n);
    const int nb = (n + 1023) / 1024;                  // 49 blocks (<= 64)
    scan_part<<<nb, 256, 0, stream>>>(deg_in, partial, n);
    scan_offsets<<<1, 64, 0, stream>>>(partial, nb, rowptr, n);
    scan_apply<<<nb, 256, 0, stream>>>(deg_in, partial, rowptr, n);
    fill_csr2<<<hblocks, 256, 0, stream>>>(src, dst, e, rowptr, cnt_in, csr_src);
    transpose_w<<<(DIN * DHID + DHID * DOF + 255) / 256, 256, 0, stream>>>(W1, W2, w1t, w2t);

    const int mtiles = (n + 127) / 128;      // 391
    const int ablocks = (n + 3) / 4;         // 4 nodes (waves) per 256-thr block

    // ---- layer 1 ----
    mfma_gemm<DIN, DHID, true><<<dim3(mtiles, DHID / 128), 256, 0, stream>>>(
        features, norm_src, w1t, h1, n);
    aggregate_wave<DHID, true, true, true><<<ablocks, 256, 0, stream>>>(
        h1, rowptr, csr_src, norm_dst, norm_src, b1, x1, n);

    // ---- layer 2 ----
    mfma_gemm<DHID, DOF, false><<<dim3(mtiles, DOF / 128), 256, 0, stream>>>(
        x1, nullptr, w2t, h2, n);
    aggregate_wave<DOF, false, false, false><<<ablocks, 256, 0, stream>>>(
        h2, rowptr, csr_src, norm_dst, norm_src, b2, out, n);
}

// Round 13
// 210.886 us; speedup vs baseline: 7.0886x; 1.0342x over previous
//
#include <hip/hip_runtime.h>
#include <type_traits>

#define DIN  512
#define DHID 256
#define DOF  128

// CSR-build partitioning: node ranges of 8192, 32 blocks share each range's edges
#define RB   13
#define RSZ  (1 << RB)      // 8192 nodes per range
#define BPR  32             // blocks per range

typedef _Float16 f16;
typedef _Float16 f16x8 __attribute__((ext_vector_type(8)));
typedef _Float16 f16v4 __attribute__((ext_vector_type(4)));
typedef _Float16 f16v2 __attribute__((ext_vector_type(2)));
typedef float f32x4 __attribute__((ext_vector_type(4)));

// ---------------- per-(range,block) LDS histograms of src/dst ----------------
__global__ __launch_bounds__(256) void hist_deg(const int* __restrict__ src,
                                                const int* __restrict__ dst, int e,
                                                int* __restrict__ cnt_out,
                                                int* __restrict__ cnt_in) {
    __shared__ int h_out[RSZ], h_in[RSZ];
    const int r = blockIdx.x / BPR, b = blockIdx.x % BPR;
    const int base = r << RB;
    const int tid = threadIdx.x;
    for (int j = tid; j < RSZ; j += 256) { h_out[j] = 0; h_in[j] = 0; }
    __syncthreads();

    const int ce = (((e + BPR - 1) / BPR) + 3) & ~3;
    const int s0 = b * ce, s1 = min(s0 + ce, e);
    for (int i = s0 + tid * 4; i < s1; i += 1024) {
        if (i + 3 < s1) {
            int4 sv = *(const int4*)(src + i);
            int4 dv = *(const int4*)(dst + i);
            int v;
            v = sv.x - base; if ((unsigned)v < RSZ) atomicAdd(&h_out[v], 1);
            v = sv.y - base; if ((unsigned)v < RSZ) atomicAdd(&h_out[v], 1);
            v = sv.z - base; if ((unsigned)v < RSZ) atomicAdd(&h_out[v], 1);
            v = sv.w - base; if ((unsigned)v < RSZ) atomicAdd(&h_out[v], 1);
            v = dv.x - base; if ((unsigned)v < RSZ) atomicAdd(&h_in[v], 1);
            v = dv.y - base; if ((unsigned)v < RSZ) atomicAdd(&h_in[v], 1);
            v = dv.z - base; if ((unsigned)v < RSZ) atomicAdd(&h_in[v], 1);
            v = dv.w - base; if ((unsigned)v < RSZ) atomicAdd(&h_in[v], 1);
        } else {
            for (int q = i; q < s1; ++q) {
                int v = src[q] - base; if ((unsigned)v < RSZ) atomicAdd(&h_out[v], 1);
                v = dst[q] - base;     if ((unsigned)v < RSZ) atomicAdd(&h_in[v], 1);
            }
        }
    }
    __syncthreads();
    int* co = cnt_out + (size_t)(r * BPR + b) * RSZ;
    int* ci = cnt_in  + (size_t)(r * BPR + b) * RSZ;
    for (int j = tid; j < RSZ; j += 256) { co[j] = h_out[j]; ci[j] = h_in[j]; }
}

// ---------------- per-node: sum counts -> deg/norms; exclusive-scan cnt_in over b ----------------
__global__ void sum_base(const int* __restrict__ cnt_out, int* __restrict__ cnt_in,
                         int* __restrict__ deg_in,
                         float* __restrict__ norm_src, float* __restrict__ norm_dst, int n) {
    int d = blockIdx.x * blockDim.x + threadIdx.x;
    if (d >= n) return;
    const int r = d >> RB, j = d & (RSZ - 1);
    int* ci = cnt_in + (size_t)(r * BPR) * RSZ + j;
    int s = 0;
#pragma unroll 4
    for (int b = 0; b < BPR; ++b) {
        int c = ci[(size_t)b * RSZ];
        ci[(size_t)b * RSZ] = s;          // in-place exclusive base
        s += c;
    }
    deg_in[d] = s;
    norm_dst[d] = rsqrtf(fmaxf((float)s, 1.0f));
    const int* co = cnt_out + (size_t)(r * BPR) * RSZ + j;
    int s2 = 0;
#pragma unroll 4
    for (int b = 0; b < BPR; ++b) s2 += co[(size_t)b * RSZ];
    norm_src[d] = rsqrtf(fmaxf((float)s2, 1.0f));
}

// ---------------- two-level exclusive scan: deg_in -> rowptr[n+1] ----------------
__global__ __launch_bounds__(256) void scan_part(const int* __restrict__ deg,
                                                 int* __restrict__ partial, int n) {
    const int base = blockIdx.x * 1024;
    const int tid = threadIdx.x;
    int v = 0;
#pragma unroll
    for (int j = 0; j < 4; ++j) {
        int i = base + tid * 4 + j;
        if (i < n) v += deg[i];
    }
    for (int o = 1; o < 64; o <<= 1) v += __shfl_xor(v, o);
    __shared__ int wsum[4];
    if ((tid & 63) == 0) wsum[tid >> 6] = v;
    __syncthreads();
    if (tid == 0) partial[blockIdx.x] = wsum[0] + wsum[1] + wsum[2] + wsum[3];
}

__global__ __launch_bounds__(64) void scan_offsets(int* __restrict__ partial, int nb,
                                                   int* __restrict__ rowptr, int n) {
    const int l = threadIdx.x;
    int orig = (l < nb) ? partial[l] : 0;
    int v = orig;
    for (int o = 1; o < 64; o <<= 1) {
        int u = __shfl_up(v, o);
        if (l >= o) v += u;
    }
    if (l < nb) partial[l] = v - orig;        // exclusive
    if (l == nb - 1) rowptr[n] = v;           // total edge count
}

__global__ __launch_bounds__(256) void scan_apply(const int* __restrict__ deg,
                                                  const int* __restrict__ partial,
                                                  int* __restrict__ rowptr, int n) {
    const int base = blockIdx.x * 1024;
    const int tid = threadIdx.x;
    int x[4]; int s = 0;
#pragma unroll
    for (int j = 0; j < 4; ++j) {
        int i = base + tid * 4 + j;
        x[j] = (i < n) ? deg[i] : 0;
        s += x[j];
    }
    const int l = tid & 63, w = tid >> 6;
    int inc = s;
    for (int o = 1; o < 64; o <<= 1) {
        int u = __shfl_up(inc, o);
        if (l >= o) inc += u;
    }
    __shared__ int wsum[4];
    if (l == 63) wsum[w] = inc;
    __syncthreads();
    int wbase = 0;
    for (int q = 0; q < w; ++q) wbase += wsum[q];
    int excl = partial[blockIdx.x] + wbase + (inc - s);
#pragma unroll
    for (int j = 0; j < 4; ++j) {
        int i = base + tid * 4 + j;
        if (i < n) rowptr[i] = excl;
        excl += x[j];
    }
}

// ---------------- fill csr_src: LDS cursors only, no global atomics ----------------
__global__ __launch_bounds__(256) void fill_csr2(const int* __restrict__ src,
                                                 const int* __restrict__ dst, int e,
                                                 const int* __restrict__ rowptr,
                                                 const int* __restrict__ base_in,
                                                 int* __restrict__ csr_src) {
    __shared__ int cur[RSZ];
    const int r = blockIdx.x / BPR, b = blockIdx.x % BPR;
    const int base = r << RB;
    const int tid = threadIdx.x;
    for (int j = tid; j < RSZ; j += 256) cur[j] = 0;
    __syncthreads();

    const int* bi = base_in + (size_t)(r * BPR + b) * RSZ;
    const int ce = (((e + BPR - 1) / BPR) + 3) & ~3;
    const int s0 = b * ce, s1 = min(s0 + ce, e);
    for (int i = s0 + tid * 4; i < s1; i += 1024) {
        if (i + 3 < s1) {
            int4 dv = *(const int4*)(dst + i);
            int4 sv = *(const int4*)(src + i);
            int v;
            v = dv.x - base; if ((unsigned)v < RSZ) { int p = atomicAdd(&cur[v], 1); csr_src[rowptr[base + v] + bi[v] + p] = sv.x; }
            v = dv.y - base; if ((unsigned)v < RSZ) { int p = atomicAdd(&cur[v], 1); csr_src[rowptr[base + v] + bi[v] + p] = sv.y; }
            v = dv.z - base; if ((unsigned)v < RSZ) { int p = atomicAdd(&cur[v], 1); csr_src[rowptr[base + v] + bi[v] + p] = sv.z; }
            v = dv.w - base; if ((unsigned)v < RSZ) { int p = atomicAdd(&cur[v], 1); csr_src[rowptr[base + v] + bi[v] + p] = sv.w; }
        } else {
            for (int q = i; q < s1; ++q) {
                int v = dst[q] - base;
                if ((unsigned)v < RSZ) { int p = atomicAdd(&cur[v], 1); csr_src[rowptr[base + v] + bi[v] + p] = src[q]; }
            }
        }
    }
}

// ---------------- W -> f16 transposed: wt[c][k] = (f16)W[k][c] ----------------
__global__ void transpose_w(const float* __restrict__ W1, const float* __restrict__ W2,
                            f16* __restrict__ w1t, f16* __restrict__ w2t) {
    int t = blockIdx.x * blockDim.x + threadIdx.x;
    if (t < DIN * DHID) {
        int k = t / DHID, c = t % DHID;
        w1t[c * DIN + k] = (f16)W1[t];
    } else {
        int u = t - DIN * DHID;
        if (u < DHID * DOF) {
            int k = u / DOF, c = u % DOF;
            w2t[c * DHID + k] = (f16)W2[u];
        }
    }
}

// ---------------- MFMA GEMM, deeper (2-set / 3-tile) prefetch ----------------
// At top of even step kt: buf0 = kt (staged), rb = kt+1 (in flight), rc = kt+2 (in flight).
// Each load-set is consumed (ds_write) 2 K-steps after issue -> 2x latency cover vs before.
template<int K, int N, bool A_F32>
__global__ __launch_bounds__(256) void mfma_gemm(const void* __restrict__ Aptr,
                                                 const float* __restrict__ norm,
                                                 const f16* __restrict__ Bt,
                                                 f16* __restrict__ H, int M) {
    constexpr int BM = 128, BN = 128, BK = 32;
    constexpr int NT = K / BK;                       // 16 (L1) / 8 (L2), even
    __shared__ __align__(16) f16 smem[BM * BN];      // 32KB total

    const int rbase = blockIdx.x * BM;
    const int nbj = blockIdx.y * BN;
    const int tid = threadIdx.x;
    const int l = tid & 63, wid = tid >> 6;
    const int wr = wid >> 1, wc = wid & 1;
    const int fr = l & 15, kg = l >> 4;

    int arow[2], achk[2];
    float ascale[2];
#pragma unroll
    for (int j = 0; j < 2; ++j) {
        int u = tid + j * 256;
        arow[j] = u >> 2; achk[j] = u & 3;
        if (A_F32) {
            int grow = rbase + arow[j];
            ascale[j] = (grow < M) ? norm[grow] : 0.0f;
        }
    }

    struct ABregs {
        float4 a0[2], a1[2];
        f16x8  a16[2];
        f16x8  b[2];
    };

    auto gload = [&](int k0) {
        ABregs r;
#pragma unroll
        for (int j = 0; j < 2; ++j) {
            int grow = rbase + arow[j];
            if (A_F32) {
                if (grow < M) {
                    const float* A = (const float*)Aptr + (long)grow * K + k0 + achk[j] * 8;
                    r.a0[j] = *(const float4*)A;
                    r.a1[j] = *(const float4*)(A + 4);
                } else {
                    r.a0[j] = make_float4(0.f, 0.f, 0.f, 0.f);
                    r.a1[j] = make_float4(0.f, 0.f, 0.f, 0.f);
                }
            } else {
                f16x8 v = {};
                if (grow < M)
                    v = *(const f16x8*)((const f16*)Aptr + (long)grow * K + k0 + achk[j] * 8);
                r.a16[j] = v;
            }
            r.b[j] = *(const f16x8*)(Bt + (long)(nbj + arow[j]) * K + k0 + achk[j] * 8);
        }
        return r;
    };

    auto swrite = [&](int buf, const ABregs& r) {
        f16* As = smem + buf * 8192;
        f16* Bs = As + 4096;
#pragma unroll
        for (int j = 0; j < 2; ++j) {
            f16x8 v;
            if (A_F32) {
                float s = ascale[j];
                v[0] = (f16)(r.a0[j].x * s); v[1] = (f16)(r.a0[j].y * s);
                v[2] = (f16)(r.a0[j].z * s); v[3] = (f16)(r.a0[j].w * s);
                v[4] = (f16)(r.a1[j].x * s); v[5] = (f16)(r.a1[j].y * s);
                v[6] = (f16)(r.a1[j].z * s); v[7] = (f16)(r.a1[j].w * s);
            } else {
                v = r.a16[j];
            }
            int ia = (arow[j] * BK + achk[j] * 8) ^ ((arow[j] & 7) << 3);
            *(f16x8*)&As[ia] = v;
            *(f16x8*)&Bs[ia] = r.b[j];
        }
    };

    f32x4 acc[4][4] = {};

    auto compute = [&](int buf) {
        const f16* As = smem + buf * 8192;
        const f16* Bs = As + 4096;
        f16x8 af[4], bf[4];
#pragma unroll
        for (int m = 0; m < 4; ++m) {
            int row = wr * 64 + m * 16 + fr;
            int ia = (row * BK + kg * 8) ^ ((row & 7) << 3);
            af[m] = *(const f16x8*)&As[ia];
        }
#pragma unroll
        for (int nf = 0; nf < 4; ++nf) {
            int c = wc * 64 + nf * 16 + fr;
            int ib = (c * BK + kg * 8) ^ ((c & 7) << 3);
            bf[nf] = *(const f16x8*)&Bs[ib];
        }
#pragma unroll
        for (int m = 0; m < 4; ++m)
#pragma unroll
            for (int nf = 0; nf < 4; ++nf)
                acc[m][nf] = __builtin_amdgcn_mfma_f32_16x16x32_f16(af[m], bf[nf], acc[m][nf], 0, 0, 0);
    };

    ABregs rb, rc;
    {
        ABregs ra = gload(0);
        swrite(0, ra);
        rb = gload(BK);                  // tile 1
        if (NT > 2) rc = gload(2 * BK);  // tile 2
    }

#pragma unroll
    for (int kt = 0; kt < NT; kt += 2) {
        // even step: buf0 = kt; rb = kt+1, rc = kt+2 in flight
        __syncthreads();
        compute(0);
        if (kt + 1 < NT) swrite(1, rb);
        if (kt + 3 < NT) rb = gload((kt + 3) * BK);
        if (kt + 1 < NT) {
            // odd step: buf1 = kt+1; rc = kt+2, rb = kt+3 in flight
            __syncthreads();
            compute(1);
            if (kt + 2 < NT) swrite(0, rc);
            if (kt + 4 < NT) rc = gload((kt + 4) * BK);
        }
    }

    __syncthreads();
#pragma unroll
    for (int m = 0; m < 4; ++m)
#pragma unroll
        for (int nf = 0; nf < 4; ++nf)
#pragma unroll
            for (int i = 0; i < 4; ++i) {
                int row = wr * 64 + m * 16 + (l >> 4) * 4 + i;
                int col = wc * 64 + nf * 16 + (l & 15);
                smem[row * BN + col] = (f16)acc[m][nf][i];
            }
    __syncthreads();
#pragma unroll
    for (int j = 0; j < 8; ++j) {
        int u = tid + j * 256;
        int row = u >> 4, cu = u & 15;
        int grow = rbase + row;
        if (grow < M)
            *(f16x8*)(H + (long)grow * N + nbj + cu * 8) =
                *(const f16x8*)&smem[row * BN + cu * 8];
    }
}

// ---------------- wave-per-node CSR aggregate, 8-deep MLP, fused epilogue ----------------
template<int F, bool RELU, bool FOLD, bool OUT_F16>
__global__ __launch_bounds__(256) void aggregate_wave(const f16* __restrict__ H,
                                                      const int* __restrict__ rowptr,
                                                      const int* __restrict__ csr_src,
                                                      const float* __restrict__ norm_dst,
                                                      const float* __restrict__ norm_src,
                                                      const float* __restrict__ bias,
                                                      void* __restrict__ outp, int n) {
    constexpr int VPL = F / 64;
    using vec = typename std::conditional<VPL == 4, f16v4, f16v2>::type;

    const int node = blockIdx.x * 4 + (threadIdx.x >> 6);
    if (node >= n) return;
    const int l = threadIdx.x & 63;
    const int c0 = l * VPL;
    const f16* __restrict__ Hc = H + c0;

    int k = rowptr[node];
    const int end = rowptr[node + 1];

    float acc[VPL] = {};
    for (; k + 7 < end; k += 8) {
        int s0 = csr_src[k];
        int s1 = csr_src[k + 1];
        int s2 = csr_src[k + 2];
        int s3 = csr_src[k + 3];
        int s4 = csr_src[k + 4];
        int s5 = csr_src[k + 5];
        int s6 = csr_src[k + 6];
        int s7 = csr_src[k + 7];
        vec v0 = *(const vec*)(Hc + (long)s0 * F);
        vec v1 = *(const vec*)(Hc + (long)s1 * F);
        vec v2 = *(const vec*)(Hc + (long)s2 * F);
        vec v3 = *(const vec*)(Hc + (long)s3 * F);
        vec v4 = *(const vec*)(Hc + (long)s4 * F);
        vec v5 = *(const vec*)(Hc + (long)s5 * F);
        vec v6 = *(const vec*)(Hc + (long)s6 * F);
        vec v7 = *(const vec*)(Hc + (long)s7 * F);
#pragma unroll
        for (int q = 0; q < VPL; ++q) acc[q] += (float)v0[q];
#pragma unroll
        for (int q = 0; q < VPL; ++q) acc[q] += (float)v1[q];
#pragma unroll
        for (int q = 0; q < VPL; ++q) acc[q] += (float)v2[q];
#pragma unroll
        for (int q = 0; q < VPL; ++q) acc[q] += (float)v3[q];
#pragma unroll
        for (int q = 0; q < VPL; ++q) acc[q] += (float)v4[q];
#pragma unroll
        for (int q = 0; q < VPL; ++q) acc[q] += (float)v5[q];
#pragma unroll
        for (int q = 0; q < VPL; ++q) acc[q] += (float)v6[q];
#pragma unroll
        for (int q = 0; q < VPL; ++q) acc[q] += (float)v7[q];
    }
    if (k + 3 < end) {
        int s0 = csr_src[k];
        int s1 = csr_src[k + 1];
        int s2 = csr_src[k + 2];
        int s3 = csr_src[k + 3];
        vec v0 = *(const vec*)(Hc + (long)s0 * F);
        vec v1 = *(const vec*)(Hc + (long)s1 * F);
        vec v2 = *(const vec*)(Hc + (long)s2 * F);
        vec v3 = *(const vec*)(Hc + (long)s3 * F);
#pragma unroll
        for (int q = 0; q < VPL; ++q) acc[q] += (float)v0[q];
#pragma unroll
        for (int q = 0; q < VPL; ++q) acc[q] += (float)v1[q];
#pragma unroll
        for (int q = 0; q < VPL; ++q) acc[q] += (float)v2[q];
#pragma unroll
        for (int q = 0; q < VPL; ++q) acc[q] += (float)v3[q];
        k += 4;
    }
    for (; k < end; ++k) {
        vec v = *(const vec*)(Hc + (long)csr_src[k] * F);
#pragma unroll
        for (int q = 0; q < VPL; ++q) acc[q] += (float)v[q];
    }

    const float nd = norm_dst[node];
    const float ns = FOLD ? norm_src[node] : 1.0f;
#pragma unroll
    for (int q = 0; q < VPL; ++q) {
        float v = acc[q] * nd + bias[c0 + q];
        if (RELU) v = fmaxf(v, 0.0f);
        acc[q] = v * ns;
    }

    if (OUT_F16) {
        vec o;
#pragma unroll
        for (int q = 0; q < VPL; ++q) o[q] = (f16)acc[q];
        *(vec*)((f16*)outp + (long)node * F + c0) = o;
    } else {
        float* op = (float*)outp + (long)node * F + c0;
        if (VPL == 2) {
            *(float2*)op = make_float2(acc[0], acc[1]);
        } else {
#pragma unroll
            for (int q = 0; q < VPL; ++q) op[q] = acc[q];
        }
    }
}

extern "C" void kernel_launch(void* const* d_in, const int* in_sizes, int n_in,
                              void* d_out, int out_size, void* d_ws, size_t ws_size,
                              hipStream_t stream) {
    const float* features = (const float*)d_in[0];
    const int*   src      = (const int*)d_in[1];
    const int*   dst      = (const int*)d_in[2];
    const float* W1       = (const float*)d_in[3];
    const float* b1       = (const float*)d_in[4];
    const float* W2       = (const float*)d_in[5];
    const float* b2       = (const float*)d_in[6];
    float* out = (float*)d_out;

    const int n = in_sizes[0] / DIN;   // 50000
    const int e = in_sizes[1];         // 800000

    const int ranges = (n + RSZ - 1) >> RB;            // 7 for n=50000
    const size_t cntsz = (size_t)ranges * BPR * RSZ;   // ints per cnt array

    // ---- workspace layout ----
    char* ws = (char*)d_ws;
    size_t off = 0;
    auto alloc = [&](size_t bytes) { size_t o = off; off += (bytes + 255) & ~(size_t)255; return o; };
    size_t o_degi   = alloc((size_t)n * 4);            // deg_in (written by sum_base)
    size_t o_nsrc   = alloc((size_t)n * 4);            // norm_src
    size_t o_ndst   = alloc((size_t)n * 4);            // norm_dst
    size_t o_rowptr = alloc((size_t)(n + 1) * 4);      // rowptr
    size_t o_part   = alloc((size_t)64 * 4);           // scan partials
    size_t o_csr    = alloc((size_t)e * 4);            // csr_src
    size_t o_cnto   = alloc(cntsz * 4);                // cnt_out
    size_t o_cnti   = alloc(cntsz * 4);                // cnt_in -> base_in (in place)
    size_t o_w1t    = alloc((size_t)DIN * DHID * 2);   // W1^T f16
    size_t o_w2t    = alloc((size_t)DHID * DOF * 2);   // W2^T f16
    size_t o_h1     = alloc((size_t)n * DHID * 2);     // h1 f16
    size_t o_x1     = alloc((size_t)n * DHID * 2);     // x1 f16 (pre-scaled by norm_src)
    size_t o_h2     = alloc((size_t)n * DOF * 2);      // h2 f16
    (void)ws_size;

    int*   deg_in   = (int*)(ws + o_degi);
    float* norm_src = (float*)(ws + o_nsrc);
    float* norm_dst = (float*)(ws + o_ndst);
    int*   rowptr   = (int*)(ws + o_rowptr);
    int*   partial  = (int*)(ws + o_part);
    int*   csr_src  = (int*)(ws + o_csr);
    int*   cnt_out  = (int*)(ws + o_cnto);
    int*   cnt_in   = (int*)(ws + o_cnti);
    f16*   w1t      = (f16*)(ws + o_w1t);
    f16*   w2t      = (f16*)(ws + o_w2t);
    f16*   h1       = (f16*)(ws + o_h1);
    f16*   x1       = (f16*)(ws + o_x1);
    f16*   h2       = (f16*)(ws + o_h2);

    // ---- graph preprocessing (no global atomics, no memsets) ----
    const int hblocks = ranges * BPR;                  // 224
    hist_deg<<<hblocks, 256, 0, stream>>>(src, dst, e, cnt_out, cnt_in);
    sum_base<<<(n + 255) / 256, 256, 0, stream>>>(cnt_out, cnt_in, deg_in,
                                                  norm_src, norm_dst, n);
    const int nb = (n + 1023) / 1024;                  // 49 blocks (<= 64)
    scan_part<<<nb, 256, 0, stream>>>(deg_in, partial, n);
    scan_offsets<<<1, 64, 0, stream>>>(partial, nb, rowptr, n);
    scan_apply<<<nb, 256, 0, stream>>>(deg_in, partial, rowptr, n);
    fill_csr2<<<hblocks, 256, 0, stream>>>(src, dst, e, rowptr, cnt_in, csr_src);
    transpose_w<<<(DIN * DHID + DHID * DOF + 255) / 256, 256, 0, stream>>>(W1, W2, w1t, w2t);

    const int mtiles = (n + 127) / 128;      // 391
    const int ablocks = (n + 3) / 4;         // 4 nodes (waves) per 256-thr block

    // ---- layer 1 ----
    mfma_gemm<DIN, DHID, true><<<dim3(mtiles, DHID / 128), 256, 0, stream>>>(
        features, norm_src, w1t, h1, n);
    aggregate_wave<DHID, true, true, true><<<ablocks, 256, 0, stream>>>(
        h1, rowptr, csr_src, norm_dst, norm_src, b1, x1, n);

    // ---- layer 2 ----
    mfma_gemm<DHID, DOF, false><<<dim3(mtiles, DOF / 128), 256, 0, stream>>>(
        x1, nullptr, w2t, h2, n);
    aggregate_wave<DOF, false, false, false><<<ablocks, 256, 0, stream>>>(
        h2, rowptr, csr_src, norm_dst, norm_src, b2, out, n);
}